// Round 2
// baseline (11093.799 us; speedup 1.0000x reference)
//
#include <hip/hip_runtime.h>
#include <math.h>

// Problem constants (from reference)
#define T_STEPS 32
#define BSZ     32
#define N_IN    64
#define H       256
#define N_OUT   64
#define E_MAX   (T_STEPS * (N_IN + H))   // 10240 error rows at the end
#define CLAMP_MIN (-2.0f)
#define CLAMP_MAX ( 2.0f)

// GEMM tiling
#define BM 64
#define BK 32

// ---------------------------------------------------------------------------
// init: zero head_h (ws is poisoned 0xAA before every launch)
// ---------------------------------------------------------------------------
__global__ void init_k(float* __restrict__ head_h) {
    int i = blockIdx.x * 256 + threadIdx.x;
    head_h[i] = 0.0f;
}

// ---------------------------------------------------------------------------
// Per-step: head_pre = head_x@W_ih + head_h@W_hh + (b_ih+b_hh)
// Also materializes the 64 new input-error rows r_i * W_ih[i,:] at [E_old, E_old+64)
// and initializes rad[b,h] = sum_i |r_i * W_ih[i,h]|  (gemm adds on top, later in stream)
// grid: Bc blocks, 256 threads (one per h). All per-sample pointers pre-offset
// to the chunk; b is the LOCAL sample index.
// ---------------------------------------------------------------------------
__global__ __launch_bounds__(256) void step_head_k(
    const float* __restrict__ Xt, const float* __restrict__ eps,
    const float* __restrict__ Wih, const float* __restrict__ Whh,
    const float* __restrict__ bih, const float* __restrict__ bhh,
    const float* __restrict__ head_h,
    float* __restrict__ err, float* __restrict__ head_pre, float* __restrict__ rad,
    int E_old)
{
    __shared__ float hx[N_IN], rr[N_IN], hh[H];
    const int b = blockIdx.x;
    const int h = threadIdx.x;
    hh[h] = head_h[b * H + h];
    if (h < N_IN) {
        float x = Xt[b * N_IN + h];
        float e = eps[b];
        float l = fmaxf(x - e, CLAMP_MIN);   // clamp(x-eps, min=)
        float u = fminf(x + e, CLAMP_MAX);   // clamp(x+eps, max=)
        hx[h] = 0.5f * (l + u);
        rr[h] = 0.5f * (u - l);              // may be negative if x-eps > 2; abs below
    }
    __syncthreads();

    float accH = bih[h] + bhh[h];
    float accR = 0.0f;
    float* errB = err + (size_t)b * E_MAX * H;
    #pragma unroll 4
    for (int i = 0; i < N_IN; ++i) {
        float w = Wih[i * H + h];
        accH += hx[i] * w;
        float v = rr[i] * w;
        accR += fabsf(v);
        errB[(size_t)(E_old + i) * H + h] = v;
    }
    #pragma unroll 4
    for (int j = 0; j < H; ++j) {
        accH += hh[j] * Whh[j * H + h];
    }
    head_pre[b * H + h] = accH;
    rad[b * H + h] = accR;   // plain store: runs before gemm's atomic adds (stream order)
}

// ---------------------------------------------------------------------------
// Per-step error propagation (the big one), IN PLACE:
//   row <- (scale ⊙ row) @ W_hh   where scale = lam_prev (per column j) for
//   rows < diag_lo (rows pending their lam), scale = 1 for the previous
//   step's diag(delta) rows [diag_lo, E).
// Accumulates rad[b,h] += sum_rows |out[row,h]| via LDS reduce + 1 atomic/col.
// grid: (E/BM, Bc), 256 threads. E and diag_lo are always multiples of BM.
// ---------------------------------------------------------------------------
__global__ __launch_bounds__(256) void gemm_step_k(
    float* __restrict__ err, const float* __restrict__ Whh,
    const float* __restrict__ lam, float* __restrict__ rad,
    int E, int diag_lo)
{
    __shared__ __align__(16) float As[BM][BK];      // 8 KB
    __shared__ __align__(16) float Ws[BK][H];       // 32 KB
    __shared__ float lam_s[H];
    __shared__ float rad_s[H];

    const int b    = blockIdx.y;
    const int row0 = blockIdx.x * BM;
    const int tid  = threadIdx.x;
    float* errB = err + (size_t)b * E_MAX * H;

    lam_s[tid] = lam[b * H + tid];
    rad_s[tid] = 0.0f;

    const int tm = tid >> 5;   // 0..7  (8 row-groups of 8)
    const int tn = tid & 31;   // 0..31 (col-groups of 8)

    float acc[8][8];
    #pragma unroll
    for (int i = 0; i < 8; ++i)
        #pragma unroll
        for (int k = 0; k < 8; ++k) acc[i][k] = 0.0f;

    __syncthreads();

    for (int kt = 0; kt < H / BK; ++kt) {
        // stage A tile (64 x 32) with pending-lambda scaling along K
        #pragma unroll
        for (int it = 0; it < 2; ++it) {
            int idx = tid + it * 256;          // 0..511 float4s
            int r   = idx >> 3;                // 0..63
            int c4  = idx & 7;                 // 0..7
            int row = row0 + r;
            float4 v = *(const float4*)(errB + (size_t)row * H + kt * BK + c4 * 4);
            if (row < diag_lo) {
                int c = kt * BK + c4 * 4;
                v.x *= lam_s[c + 0]; v.y *= lam_s[c + 1];
                v.z *= lam_s[c + 2]; v.w *= lam_s[c + 3];
            }
            *(float4*)&As[r][c4 * 4] = v;
        }
        // stage W tile (32 x 256)
        #pragma unroll
        for (int it = 0; it < 8; ++it) {
            int idx = tid + it * 256;          // 0..2047 float4s
            int r   = idx >> 6;                // 0..31
            int c4  = idx & 63;                // 0..63
            *(float4*)&Ws[r][c4 * 4] =
                *(const float4*)(Whh + (size_t)(kt * BK + r) * H + c4 * 4);
        }
        __syncthreads();

        #pragma unroll 4
        for (int j = 0; j < BK; ++j) {
            float4 w0 = *(const float4*)&Ws[j][tn * 8];
            float4 w1 = *(const float4*)&Ws[j][tn * 8 + 4];
            float a[8];
            #pragma unroll
            for (int i = 0; i < 8; ++i) a[i] = As[tm * 8 + i][j];
            #pragma unroll
            for (int i = 0; i < 8; ++i) {
                acc[i][0] = fmaf(a[i], w0.x, acc[i][0]);
                acc[i][1] = fmaf(a[i], w0.y, acc[i][1]);
                acc[i][2] = fmaf(a[i], w0.z, acc[i][2]);
                acc[i][3] = fmaf(a[i], w0.w, acc[i][3]);
                acc[i][4] = fmaf(a[i], w1.x, acc[i][4]);
                acc[i][5] = fmaf(a[i], w1.y, acc[i][5]);
                acc[i][6] = fmaf(a[i], w1.z, acc[i][6]);
                acc[i][7] = fmaf(a[i], w1.w, acc[i][7]);
            }
        }
        __syncthreads();
    }

    // write back (in place) + per-column |.| partial sums
    #pragma unroll
    for (int i = 0; i < 8; ++i) {
        int row = row0 + tm * 8 + i;
        float* dst = errB + (size_t)row * H + tn * 8;
        *(float4*)dst       = make_float4(acc[i][0], acc[i][1], acc[i][2], acc[i][3]);
        *(float4*)(dst + 4) = make_float4(acc[i][4], acc[i][5], acc[i][6], acc[i][7]);
    }
    #pragma unroll
    for (int k = 0; k < 8; ++k) {
        float s = 0.0f;
        #pragma unroll
        for (int i = 0; i < 8; ++i) s += fabsf(acc[i][k]);
        atomicAdd(&rad_s[tn * 8 + k], s);
    }
    __syncthreads();
    atomicAdd(&rad[b * H + tid], rad_s[tid]);
}

// ---------------------------------------------------------------------------
// Per-step tanh transformer: lam/mu/delta from (head_pre, rad); stores lam
// (pending scale for next step), head_h = lam*head+mu, and materializes the
// dense diag(delta) block at rows [E_cat, E_cat+H).
// grid: Bc blocks, 256 threads
// ---------------------------------------------------------------------------
__global__ __launch_bounds__(256) void tanh_step_k(
    const float* __restrict__ head_pre, const float* __restrict__ rad,
    float* __restrict__ lam, float* __restrict__ head_h,
    float* __restrict__ err, int E_cat)
{
    __shared__ float de_s[H];
    const int b = blockIdx.x;
    const int h = threadIdx.x;
    float hd = head_pre[b * H + h];
    float r  = rad[b * H + h];
    float l = hd - r, u = hd + r;
    float tl = tanhf(l), tu = tanhf(u);
    float la = fminf(1.0f - tl * tl, 1.0f - tu * tu);
    float mu = 0.5f * (tu + tl - la * (u + l));
    float de = 0.5f * (tu - tl - la * (u - l));
    lam[b * H + h]    = la;
    head_h[b * H + h] = la * hd + mu;
    de_s[h] = de;
    __syncthreads();
    float* base = err + (size_t)b * E_MAX * H + (size_t)E_cat * H;
    for (int r0 = 0; r0 < H; ++r0) {
        base[(size_t)r0 * H + h] = (h == r0) ? de_s[r0] : 0.0f;  // coalesced
    }
}

// ---------------------------------------------------------------------------
// Final head: head_out = head_h @ W_o + b_o ; zeroes rad_out
// grid: Bc blocks, 64 threads
// ---------------------------------------------------------------------------
__global__ void head_out_k(
    const float* __restrict__ head_h, const float* __restrict__ Wo,
    const float* __restrict__ bo,
    float* __restrict__ head_out, float* __restrict__ rad_out)
{
    const int b = blockIdx.x;
    const int o = threadIdx.x;
    float acc = bo[o];
    #pragma unroll 4
    for (int j = 0; j < H; ++j) acc += head_h[b * H + j] * Wo[j * N_OUT + o];
    head_out[b * N_OUT + o] = acc;
    rad_out[b * N_OUT + o]  = 0.0f;
}

// ---------------------------------------------------------------------------
// Final radius: rad_out[b,o] += sum_rows |(scale ⊙ row) @ W_o[:,o]|
// Same staging/tiling as gemm_step but N=64 (2 cols per thread).
// grid: (E_MAX/BM, Bc), 256 threads
// ---------------------------------------------------------------------------
__global__ __launch_bounds__(256) void rad_out_k(
    const float* __restrict__ err, const float* __restrict__ Wo,
    const float* __restrict__ lam, float* __restrict__ rad_out,
    int diag_lo)
{
    __shared__ __align__(16) float As[BM][BK];
    __shared__ __align__(16) float Ws[BK][N_OUT];   // 8 KB
    __shared__ float lam_s[H];
    __shared__ float rad_s[N_OUT];

    const int b    = blockIdx.y;
    const int row0 = blockIdx.x * BM;
    const int tid  = threadIdx.x;
    const float* errB = err + (size_t)b * E_MAX * H;

    lam_s[tid] = lam[b * H + tid];
    if (tid < N_OUT) rad_s[tid] = 0.0f;

    const int tm = tid >> 5;   // 0..7
    const int tn = tid & 31;   // 0..31, 2 cols each

    float acc[8][2];
    #pragma unroll
    for (int i = 0; i < 8; ++i) { acc[i][0] = 0.0f; acc[i][1] = 0.0f; }

    __syncthreads();

    for (int kt = 0; kt < H / BK; ++kt) {
        #pragma unroll
        for (int it = 0; it < 2; ++it) {
            int idx = tid + it * 256;
            int r   = idx >> 3;
            int c4  = idx & 7;
            int row = row0 + r;
            float4 v = *(const float4*)(errB + (size_t)row * H + kt * BK + c4 * 4);
            if (row < diag_lo) {
                int c = kt * BK + c4 * 4;
                v.x *= lam_s[c + 0]; v.y *= lam_s[c + 1];
                v.z *= lam_s[c + 2]; v.w *= lam_s[c + 3];
            }
            *(float4*)&As[r][c4 * 4] = v;
        }
        {   // W_o tile: 32 x 64 = 512 float4s, 2 per thread
            #pragma unroll
            for (int it = 0; it < 2; ++it) {
                int idx = tid + it * 256;
                int r   = idx >> 4;            // 0..31
                int c4  = idx & 15;            // 0..15
                *(float4*)&Ws[r][c4 * 4] =
                    *(const float4*)(Wo + (size_t)(kt * BK + r) * N_OUT + c4 * 4);
            }
        }
        __syncthreads();

        #pragma unroll 4
        for (int j = 0; j < BK; ++j) {
            float w0 = Ws[j][tn * 2];
            float w1 = Ws[j][tn * 2 + 1];
            #pragma unroll
            for (int i = 0; i < 8; ++i) {
                float a = As[tm * 8 + i][j];
                acc[i][0] = fmaf(a, w0, acc[i][0]);
                acc[i][1] = fmaf(a, w1, acc[i][1]);
            }
        }
        __syncthreads();
    }

    #pragma unroll
    for (int c = 0; c < 2; ++c) {
        float s = 0.0f;
        #pragma unroll
        for (int i = 0; i < 8; ++i) s += fabsf(acc[i][c]);
        atomicAdd(&rad_s[tn * 2 + c], s);
    }
    __syncthreads();
    if (tid < N_OUT) atomicAdd(&rad_out[b * N_OUT + tid], rad_s[tid]);
}

// ---------------------------------------------------------------------------
// out[0,b,o] = head_out - rad_out ; out[1,b,o] = head_out + rad_out
// ---------------------------------------------------------------------------
__global__ void combine_k(const float* __restrict__ head_out,
                          const float* __restrict__ rad_out,
                          float* __restrict__ out)
{
    int i = blockIdx.x * 256 + threadIdx.x;
    if (i < BSZ * N_OUT) {
        float h = head_out[i], r = rad_out[i];
        out[i]                = h - r;
        out[BSZ * N_OUT + i]  = h + r;
    }
}

// ---------------------------------------------------------------------------
extern "C" void kernel_launch(void* const* d_in, const int* in_sizes, int n_in,
                              void* d_out, int out_size, void* d_ws, size_t ws_size,
                              hipStream_t stream)
{
    const float* X    = (const float*)d_in[0];  // [T,B,N_IN]
    const float* eps  = (const float*)d_in[1];  // [B]
    const float* Wih  = (const float*)d_in[2];  // [N_IN,H]
    const float* Whh  = (const float*)d_in[3];  // [H,H]
    const float* bih  = (const float*)d_in[4];  // [H]
    const float* bhh  = (const float*)d_in[5];  // [H]
    const float* Wo   = (const float*)d_in[6];  // [H,N_OUT]
    const float* bo   = (const float*)d_in[7];  // [N_OUT]
    float* out = (float*)d_out;                 // [2,B,N_OUT]

    // Adaptive batch chunking: err chunk needs Bc * E_MAX * H * 4 bytes.
    // ws_size is constant across calls -> deterministic schedule (capture-safe).
    const size_t chunk_bytes = (size_t)E_MAX * H * sizeof(float);   // per-sample: 10.49 MB
    const size_t small_bytes = (size_t)(4 * BSZ * H + 2 * BSZ * N_OUT) * sizeof(float);
    int Bc = BSZ;
    while (Bc > 1 && (size_t)Bc * chunk_bytes + small_bytes > ws_size) Bc >>= 1;

    // workspace carve-up
    float* err      = (float*)d_ws;                        // [Bc, E_MAX, H]
    float* head_pre = err + (size_t)Bc * E_MAX * H;        // [BSZ, H]
    float* head_h   = head_pre + BSZ * H;                  // [BSZ, H]
    float* rad      = head_h   + BSZ * H;                  // [BSZ, H]
    float* lam      = rad      + BSZ * H;                  // [BSZ, H]
    float* head_out = lam      + BSZ * H;                  // [BSZ, N_OUT]
    float* rad_out  = head_out + BSZ * N_OUT;              // [BSZ, N_OUT]

    init_k<<<(BSZ * H) / 256, 256, 0, stream>>>(head_h);

    for (int b0 = 0; b0 < BSZ; b0 += Bc) {
        for (int t = 0; t < T_STEPS; ++t) {
            int E_old   = t * (N_IN + H);                 // live rows (multiple of 64)
            int diag_lo = (t == 0) ? 0 : (E_old - H);     // prev diag rows carry scale 1
            step_head_k<<<Bc, 256, 0, stream>>>(
                X + (size_t)(t * BSZ + b0) * N_IN, eps + b0, Wih, Whh, bih, bhh,
                head_h + (size_t)b0 * H, err,
                head_pre + (size_t)b0 * H, rad + (size_t)b0 * H, E_old);
            if (E_old > 0) {
                gemm_step_k<<<dim3(E_old / BM, Bc), 256, 0, stream>>>(
                    err, Whh, lam + (size_t)b0 * H, rad + (size_t)b0 * H,
                    E_old, diag_lo);
            }
            tanh_step_k<<<Bc, 256, 0, stream>>>(
                head_pre + (size_t)b0 * H, rad + (size_t)b0 * H,
                lam + (size_t)b0 * H, head_h + (size_t)b0 * H,
                err, E_old + N_IN);
        }
        head_out_k<<<Bc, 64, 0, stream>>>(
            head_h + (size_t)b0 * H, Wo, bo,
            head_out + (size_t)b0 * N_OUT, rad_out + (size_t)b0 * N_OUT);
        rad_out_k<<<dim3(E_MAX / BM, Bc), 256, 0, stream>>>(
            err, Wo, lam + (size_t)b0 * H,
            rad_out + (size_t)b0 * N_OUT, E_MAX - H);
    }

    combine_k<<<(BSZ * N_OUT + 255) / 256, 256, 0, stream>>>(head_out, rad_out, out);
}

// Round 3
// 5321.368 us; speedup vs baseline: 2.0848x; 2.0848x over previous
//
#include <hip/hip_runtime.h>
#include <math.h>

typedef unsigned short ushort_t;
typedef __attribute__((ext_vector_type(8))) short bf16x8;   // MFMA A/B frag (4 VGPR)
typedef __attribute__((ext_vector_type(4))) float f32x4;    // MFMA C/D frag

// Problem constants
#define T_STEPS 32
#define BSZ     32
#define N_IN    64
#define H       256
#define N_OUT   64
#define E_MAX   (T_STEPS * (N_IN + H))   // 10240
#define CLAMP_MIN (-2.0f)
#define CLAMP_MAX ( 2.0f)

// fp32 fallback GEMM tiling (final radius kernel)
#define BM 64
#define BK 32

__device__ inline void split_bf16(float x, ushort_t& h, ushort_t& l) {
    unsigned u = __builtin_bit_cast(unsigned, x);
    h = (ushort_t)(u >> 16);                                  // truncate to bf16
    float hf = __builtin_bit_cast(float, u & 0xFFFF0000u);
    float lo = x - hf;                                        // exact remainder
    l = (ushort_t)(__builtin_bit_cast(unsigned, lo) >> 16);
}

// ---------------------------------------------------------------------------
__global__ void init_k(float* __restrict__ head_h) {
    int i = blockIdx.x * 256 + threadIdx.x;
    head_h[i] = 0.0f;
}

// ---------------------------------------------------------------------------
// Pack W_hh (row-major [H][H] fp32) into hi/lo bf16 fragment-ordered buffers:
// Wp[((kc*16 + nt)*64 + lane)*8 + j] = W[kc*32 + (lane>>4)*8 + j][nt*16 + (lane&15)]
// grid 32 x 256 (8192 threads, one per (kc,nt,lane))
// ---------------------------------------------------------------------------
__global__ void pack_whh_k(const float* __restrict__ W,
                           ushort_t* __restrict__ Wh, ushort_t* __restrict__ Wl)
{
    int g = blockIdx.x * 256 + threadIdx.x;     // [0, 8192)
    int kc = g >> 10, nt = (g >> 6) & 15, lane = g & 63;
    int q = lane >> 4, m = lane & 15;
    union { ushort_t us[8]; uint4 v; } uh, ul;
    #pragma unroll
    for (int j = 0; j < 8; ++j) {
        float x = W[(kc * 32 + q * 8 + j) * H + nt * 16 + m];
        split_bf16(x, uh.us[j], ul.us[j]);
    }
    *(uint4*)&Wh[(size_t)g * 8] = uh.v;
    *(uint4*)&Wl[(size_t)g * 8] = ul.v;
}

// ---------------------------------------------------------------------------
// step_head: head_pre = head_x@W_ih + head_h@W_hh + bias; writes the 64 fresh
// input-error rows; initializes rad. grid: Bc x 256 (pointers pre-offset).
// ---------------------------------------------------------------------------
__global__ __launch_bounds__(256) void step_head_k(
    const float* __restrict__ Xt, const float* __restrict__ eps,
    const float* __restrict__ Wih, const float* __restrict__ Whh,
    const float* __restrict__ bih, const float* __restrict__ bhh,
    const float* __restrict__ head_h,
    float* __restrict__ err, float* __restrict__ head_pre, float* __restrict__ rad,
    int E_old)
{
    __shared__ float hx[N_IN], rr[N_IN], hh[H];
    const int b = blockIdx.x;
    const int h = threadIdx.x;
    hh[h] = head_h[b * H + h];
    if (h < N_IN) {
        float x = Xt[b * N_IN + h];
        float e = eps[b];
        float l = fmaxf(x - e, CLAMP_MIN);
        float u = fminf(x + e, CLAMP_MAX);
        hx[h] = 0.5f * (l + u);
        rr[h] = 0.5f * (u - l);
    }
    __syncthreads();

    float accH = bih[h] + bhh[h];
    float accR = 0.0f;
    float* errB = err + (size_t)b * E_MAX * H;
    #pragma unroll 4
    for (int i = 0; i < N_IN; ++i) {
        float w = Wih[i * H + h];
        accH += hx[i] * w;
        float v = rr[i] * w;
        accR += fabsf(v);
        errB[(size_t)(E_old + i) * H + h] = v;
    }
    #pragma unroll 4
    for (int j = 0; j < H; ++j) accH += hh[j] * Whh[j * H + h];
    head_pre[b * H + h] = accH;
    rad[b * H + h] = accR;
}

// ---------------------------------------------------------------------------
// MFMA error-propagation GEMM, in place, split-bf16 (3 products):
//   rows <  diag_lo : A = lam ⊙ err-row (pending scale from prev tanh)
//   rows in [diag_lo,E): analytic diag rows, A[r][k] = (k == r-diag_lo)?de[k]:0
//   rows >= E       : zero (tile padding)
// C written back fp32; rad[b,h] += sum_rows |C[row,h]|.
// Block tile 128x256, 4 waves, each wave 64 rows x 128 cols.
// grid: (ceil(E/128), Bc), 256 threads.
// ---------------------------------------------------------------------------
__global__ __launch_bounds__(256, 2) void gemm_mfma_k(
    float* __restrict__ err,
    const ushort_t* __restrict__ Wh, const ushort_t* __restrict__ Wl,
    const float* __restrict__ lam, const float* __restrict__ de,
    float* __restrict__ rad, int E, int diag_lo)
{
    __shared__ ushort_t ahs[8 * 64 * 8];   // A-hi frags: [rt 0..7][lane][j]  8 KB
    __shared__ ushort_t als[8 * 64 * 8];   // A-lo frags                      8 KB
    __shared__ float lam_s[H];
    __shared__ float de_s[H];
    __shared__ float rad_s[H];

    const int b    = blockIdx.y;
    const int row0 = blockIdx.x * 128;
    const int tid  = threadIdx.x;
    const int wave = tid >> 6;
    const int lane = tid & 63;
    float* errB = err + (size_t)b * E_MAX * H;

    lam_s[tid] = lam[b * H + tid];
    de_s[tid]  = de[b * H + tid];
    rad_s[tid] = 0.0f;

    f32x4 acc[4][8];
    #pragma unroll
    for (int i = 0; i < 4; ++i)
        #pragma unroll
        for (int c = 0; c < 8; ++c) acc[i][c] = (f32x4){0.f, 0.f, 0.f, 0.f};

    __syncthreads();

    for (int kc = 0; kc < 8; ++kc) {
        // ---- stage A tile (128 rows x 32 k) as packed bf16 hi/lo fragments
        #pragma unroll
        for (int it = 0; it < 2; ++it) {
            int task = tid + it * 256;         // [0,512): 128 rows x 4 kq
            int kq = task & 3;
            int r  = task >> 2;
            int row_g = row0 + r;
            float v[8];
            if (row_g < diag_lo) {
                const float* src = errB + (size_t)row_g * H + kc * 32 + kq * 8;
                #pragma unroll
                for (int j = 0; j < 8; ++j) v[j] = src[j] * lam_s[kc * 32 + kq * 8 + j];
            } else if (row_g < E) {            // analytic diag row from prev tanh
                int i0 = row_g - diag_lo;      // nonzero col
                #pragma unroll
                for (int j = 0; j < 8; ++j) v[j] = 0.0f;
                int kb = kc * 32 + kq * 8;
                if (i0 >= kb && i0 < kb + 8) v[i0 - kb] = de_s[i0];
            } else {
                #pragma unroll
                for (int j = 0; j < 8; ++j) v[j] = 0.0f;
            }
            union { ushort_t us[8]; uint4 q; } uh, ul;
            #pragma unroll
            for (int j = 0; j < 8; ++j) split_bf16(v[j], uh.us[j], ul.us[j]);
            int idx = ((r >> 4) * 64 + kq * 16 + (r & 15)) * 8;  // [rt][lane=kq*16+m][j]
            *(uint4*)&ahs[idx] = uh.q;
            *(uint4*)&als[idx] = ul.q;
        }
        __syncthreads();

        // ---- compute: wave (wave>>1) row half, (wave&1) col half
        bf16x8 ah[4], al[4];
        #pragma unroll
        for (int i = 0; i < 4; ++i) {
            int rt = (wave >> 1) * 4 + i;
            ah[i] = *(const bf16x8*)&ahs[(rt * 64 + lane) * 8];
            al[i] = *(const bf16x8*)&als[(rt * 64 + lane) * 8];
        }
        for (int c = 0; c < 8; ++c) {
            int nt = (wave & 1) * 8 + c;
            size_t boff = ((size_t)(kc * 16 + nt) * 64 + lane) * 8;
            bf16x8 bh = *(const bf16x8*)&Wh[boff];
            bf16x8 bl = *(const bf16x8*)&Wl[boff];
            #pragma unroll
            for (int i = 0; i < 4; ++i) {
                acc[i][c] = __builtin_amdgcn_mfma_f32_16x16x32_bf16(ah[i], bh, acc[i][c], 0, 0, 0);
                acc[i][c] = __builtin_amdgcn_mfma_f32_16x16x32_bf16(ah[i], bl, acc[i][c], 0, 0, 0);
                acc[i][c] = __builtin_amdgcn_mfma_f32_16x16x32_bf16(al[i], bh, acc[i][c], 0, 0, 0);
            }
        }
        __syncthreads();
    }

    // ---- writeback (C/D layout: col = lane&15, row = (lane>>4)*4 + reg) + rad
    const int rowb = row0 + (wave >> 1) * 64;
    const int colb = (wave & 1) * 128;
    #pragma unroll
    for (int c = 0; c < 8; ++c) {
        int col_g = colb + c * 16 + (lane & 15);
        float s = 0.0f;
        #pragma unroll
        for (int i = 0; i < 4; ++i) {
            int rbase = rowb + i * 16 + (lane >> 4) * 4;
            #pragma unroll
            for (int r = 0; r < 4; ++r) {
                float v = acc[i][c][r];
                int row_g = rbase + r;
                if (row_g < E) errB[(size_t)row_g * H + col_g] = v;
                s += fabsf(v);
            }
        }
        atomicAdd(&rad_s[col_g], s);
    }
    __syncthreads();
    atomicAdd(&rad[b * H + tid], rad_s[tid]);
}

// ---------------------------------------------------------------------------
// tanh transformer: lam/mu/delta; stores lam, head_h, de (diag NOT materialized)
// grid: Bc x 256
// ---------------------------------------------------------------------------
__global__ __launch_bounds__(256) void tanh_step_k(
    const float* __restrict__ head_pre, const float* __restrict__ rad,
    float* __restrict__ lam, float* __restrict__ head_h, float* __restrict__ de)
{
    const int b = blockIdx.x;
    const int h = threadIdx.x;
    float hd = head_pre[b * H + h];
    float r  = rad[b * H + h];
    float l = hd - r, u = hd + r;
    float tl = tanhf(l), tu = tanhf(u);
    float la = fminf(1.0f - tl * tl, 1.0f - tu * tu);
    float mu = 0.5f * (tu + tl - la * (u + l));
    float dd = 0.5f * (tu - tl - la * (u - l));
    lam[b * H + h]    = la;
    head_h[b * H + h] = la * hd + mu;
    de[b * H + h]     = dd;
}

// ---------------------------------------------------------------------------
// Final head + last diag block's radius contribution:
// head_out = head_h@W_o + b_o ; rad_out = sum_i |de_last[i] * W_o[i,:]|
// grid: Bc x 64
// ---------------------------------------------------------------------------
__global__ void head_out_k(
    const float* __restrict__ head_h, const float* __restrict__ de,
    const float* __restrict__ Wo, const float* __restrict__ bo,
    float* __restrict__ head_out, float* __restrict__ rad_out)
{
    const int b = blockIdx.x;
    const int o = threadIdx.x;
    float acc = bo[o];
    float accR = 0.0f;
    #pragma unroll 4
    for (int j = 0; j < H; ++j) {
        float w = Wo[j * N_OUT + o];
        acc  += head_h[b * H + j] * w;
        accR += fabsf(de[b * H + j] * w);
    }
    head_out[b * N_OUT + o] = acc;
    rad_out[b * N_OUT + o]  = accR;
}

// ---------------------------------------------------------------------------
// Final radius over dense rows [0, E_MAX-H): rad_out += sum_rows |(lam⊙row)@W_o|
// fp32 tile GEMM (small: ~10 GFLOP total). grid: ((E_MAX-H)/BM, Bc)
// ---------------------------------------------------------------------------
__global__ __launch_bounds__(256) void rad_out_k(
    const float* __restrict__ err, const float* __restrict__ Wo,
    const float* __restrict__ lam, float* __restrict__ rad_out)
{
    __shared__ __align__(16) float As[BM][BK];
    __shared__ __align__(16) float Ws[BK][N_OUT];
    __shared__ float lam_s[H];
    __shared__ float rad_s[N_OUT];

    const int b    = blockIdx.y;
    const int row0 = blockIdx.x * BM;
    const int tid  = threadIdx.x;
    const float* errB = err + (size_t)b * E_MAX * H;

    lam_s[tid] = lam[b * H + tid];
    if (tid < N_OUT) rad_s[tid] = 0.0f;

    const int tm = tid >> 5;
    const int tn = tid & 31;

    float acc[8][2];
    #pragma unroll
    for (int i = 0; i < 8; ++i) { acc[i][0] = 0.0f; acc[i][1] = 0.0f; }

    __syncthreads();

    for (int kt = 0; kt < H / BK; ++kt) {
        #pragma unroll
        for (int it = 0; it < 2; ++it) {
            int idx = tid + it * 256;
            int r   = idx >> 3;
            int c4  = idx & 7;
            int row = row0 + r;
            float4 v = *(const float4*)(errB + (size_t)row * H + kt * BK + c4 * 4);
            int c = kt * BK + c4 * 4;
            v.x *= lam_s[c + 0]; v.y *= lam_s[c + 1];
            v.z *= lam_s[c + 2]; v.w *= lam_s[c + 3];
            *(float4*)&As[r][c4 * 4] = v;
        }
        #pragma unroll
        for (int it = 0; it < 2; ++it) {
            int idx = tid + it * 256;
            int r   = idx >> 4;
            int c4  = idx & 15;
            *(float4*)&Ws[r][c4 * 4] =
                *(const float4*)(Wo + (size_t)(kt * BK + r) * N_OUT + c4 * 4);
        }
        __syncthreads();

        #pragma unroll 4
        for (int j = 0; j < BK; ++j) {
            float w0 = Ws[j][tn * 2];
            float w1 = Ws[j][tn * 2 + 1];
            #pragma unroll
            for (int i = 0; i < 8; ++i) {
                float a = As[tm * 8 + i][j];
                acc[i][0] = fmaf(a, w0, acc[i][0]);
                acc[i][1] = fmaf(a, w1, acc[i][1]);
            }
        }
        __syncthreads();
    }

    #pragma unroll
    for (int c = 0; c < 2; ++c) {
        float s = 0.0f;
        #pragma unroll
        for (int i = 0; i < 8; ++i) s += fabsf(acc[i][c]);
        atomicAdd(&rad_s[tn * 2 + c], s);
    }
    __syncthreads();
    if (tid < N_OUT) atomicAdd(&rad_out[b * N_OUT + tid], rad_s[tid]);
}

// ---------------------------------------------------------------------------
__global__ void combine_k(const float* __restrict__ head_out,
                          const float* __restrict__ rad_out,
                          float* __restrict__ out)
{
    int i = blockIdx.x * 256 + threadIdx.x;
    if (i < BSZ * N_OUT) {
        float h = head_out[i], r = rad_out[i];
        out[i]               = h - r;
        out[BSZ * N_OUT + i] = h + r;
    }
}

// ---------------------------------------------------------------------------
extern "C" void kernel_launch(void* const* d_in, const int* in_sizes, int n_in,
                              void* d_out, int out_size, void* d_ws, size_t ws_size,
                              hipStream_t stream)
{
    const float* X    = (const float*)d_in[0];
    const float* eps  = (const float*)d_in[1];
    const float* Wih  = (const float*)d_in[2];
    const float* Whh  = (const float*)d_in[3];
    const float* bih  = (const float*)d_in[4];
    const float* bhh  = (const float*)d_in[5];
    const float* Wo   = (const float*)d_in[6];
    const float* bo   = (const float*)d_in[7];
    float* out = (float*)d_out;

    // small-buffer region size (floats): 5*BSZ*H + 2*BSZ*N_OUT + packed W (as floats)
    const size_t packed_floats = (H * H) + (H * H) / 1;   // 65536 us *2 = 65536 floats
    const size_t small_f = (size_t)5 * BSZ * H + 2 * BSZ * N_OUT + packed_floats + 64;
    const size_t chunk_bytes = (size_t)E_MAX * H * sizeof(float);
    int Bc = BSZ;
    while (Bc > 1 && (size_t)Bc * chunk_bytes + small_f * sizeof(float) > ws_size) Bc >>= 1;

    float* err      = (float*)d_ws;                        // [Bc, E_MAX, H]
    float* head_pre = err + (size_t)Bc * E_MAX * H;        // [BSZ, H]
    float* head_h   = head_pre + BSZ * H;
    float* rad      = head_h   + BSZ * H;
    float* lam      = rad      + BSZ * H;
    float* de       = lam      + BSZ * H;
    float* head_out = de       + BSZ * H;                  // [BSZ, N_OUT]
    float* rad_out  = head_out + BSZ * N_OUT;
    ushort_t* Whh_h = (ushort_t*)(rad_out + BSZ * N_OUT);  // [65536]
    ushort_t* Whh_l = Whh_h + (size_t)H * H;               // [65536]

    pack_whh_k<<<32, 256, 0, stream>>>(Whh, Whh_h, Whh_l);
    init_k<<<(BSZ * H) / 256, 256, 0, stream>>>(head_h);

    for (int b0 = 0; b0 < BSZ; b0 += Bc) {
        for (int t = 0; t < T_STEPS; ++t) {
            int E_old   = t * (N_IN + H);
            int diag_lo = (t == 0) ? 0 : (E_old - H);
            step_head_k<<<Bc, 256, 0, stream>>>(
                X + (size_t)(t * BSZ + b0) * N_IN, eps + b0, Wih, Whh, bih, bhh,
                head_h + (size_t)b0 * H, err,
                head_pre + (size_t)b0 * H, rad + (size_t)b0 * H, E_old);
            if (E_old > 0) {
                gemm_mfma_k<<<dim3((E_old + 127) / 128, Bc), 256, 0, stream>>>(
                    err, Whh_h, Whh_l,
                    lam + (size_t)b0 * H, de + (size_t)b0 * H,
                    rad + (size_t)b0 * H, E_old, diag_lo);
            }
            tanh_step_k<<<Bc, 256, 0, stream>>>(
                head_pre + (size_t)b0 * H, rad + (size_t)b0 * H,
                lam + (size_t)b0 * H, head_h + (size_t)b0 * H,
                de + (size_t)b0 * H);
        }
        head_out_k<<<Bc, 64, 0, stream>>>(
            head_h + (size_t)b0 * H, de + (size_t)b0 * H, Wo, bo,
            head_out + (size_t)b0 * N_OUT, rad_out + (size_t)b0 * N_OUT);
        rad_out_k<<<dim3((E_MAX - H) / BM, Bc), 256, 0, stream>>>(
            err, Wo, lam + (size_t)b0 * H, rad_out + (size_t)b0 * N_OUT);
    }

    combine_k<<<(BSZ * N_OUT + 255) / 256, 256, 0, stream>>>(head_out, rad_out, out);
}

// Round 4
// 3562.405 us; speedup vs baseline: 3.1141x; 1.4938x over previous
//
#include <hip/hip_runtime.h>
#include <math.h>

typedef unsigned short ushort_t;
typedef __attribute__((ext_vector_type(8))) short bf16x8;   // MFMA A/B frag
typedef __attribute__((ext_vector_type(4))) float f32x4;    // MFMA C/D frag

#define T_STEPS 32
#define BSZ     32
#define N_IN    64
#define H       256
#define N_OUT   64
#define ESTRIDE 9984              // max materialized err rows = 320*31 + 64
#define CLAMP_MIN (-2.0f)
#define CLAMP_MAX ( 2.0f)

__device__ inline ushort_t f2bf(float x) {                  // RTNE fp32->bf16
    unsigned u = __builtin_bit_cast(unsigned, x);
    unsigned r = u + 0x7FFFu + ((u >> 16) & 1u);
    return (ushort_t)(r >> 16);
}

// ---------------------------------------------------------------------------
// One-time fp32 transpose: dst[C][R] = src[R][C]^T. grid (C/32, R/32), 256 thr
// ---------------------------------------------------------------------------
__global__ void transpose_k(const float* __restrict__ src, float* __restrict__ dst,
                            int R, int C)
{
    __shared__ float tile[32][33];
    int bi = blockIdx.y, bj = blockIdx.x;
    int r0 = threadIdx.x >> 5, c = threadIdx.x & 31;
    #pragma unroll
    for (int rr = 0; rr < 4; ++rr) {
        int r = r0 * 4 + rr;
        tile[r][c] = src[(bi * 32 + r) * C + bj * 32 + c];
    }
    __syncthreads();
    #pragma unroll
    for (int rr = 0; rr < 4; ++rr) {
        int r = r0 * 4 + rr;
        dst[(bj * 32 + r) * R + bi * 32 + c] = tile[c][r];
    }
}

// ---------------------------------------------------------------------------
// prep: (t>0) tanh of prev step -> lam/de/head_h(local); head_pre_t; fresh
// input-error rows [E_old, E_old+64) in bf16; rad init. grid Bc x 256.
// ---------------------------------------------------------------------------
__global__ __launch_bounds__(256) void prep_k(
    const float* __restrict__ Xt, const float* __restrict__ eps,
    const float* __restrict__ Wih, const float* __restrict__ Whh,
    const float* __restrict__ bih, const float* __restrict__ bhh,
    float* __restrict__ head_pre, float* __restrict__ rad,
    float* __restrict__ lam, float* __restrict__ de,
    ushort_t* __restrict__ err, int E_old, int is_t0)
{
    __shared__ float hx[N_IN], rr[N_IN], hh[H];
    const int b = blockIdx.x, h = threadIdx.x;
    float hh_val = 0.0f;
    if (!is_t0) {
        float hd = head_pre[b * H + h], r = rad[b * H + h];
        float l = hd - r, u = hd + r;
        float tl = tanhf(l), tu = tanhf(u);
        float la = fminf(1.f - tl * tl, 1.f - tu * tu);
        float mu = 0.5f * (tu + tl - la * (u + l));
        float dd = 0.5f * (tu - tl - la * (u - l));
        lam[b * H + h] = la;
        de[b * H + h]  = dd;
        hh_val = la * hd + mu;
    }
    hh[h] = hh_val;
    if (h < N_IN) {
        float x = Xt[b * N_IN + h], e = eps[b];
        float l = fmaxf(x - e, CLAMP_MIN);
        float u = fminf(x + e, CLAMP_MAX);
        hx[h] = 0.5f * (l + u);
        rr[h] = 0.5f * (u - l);
    }
    __syncthreads();
    float accH = bih[h] + bhh[h], accR = 0.f;
    ushort_t* errB = err + (size_t)b * ESTRIDE * H;
    #pragma unroll 8
    for (int i = 0; i < N_IN; ++i) {
        float w = Wih[i * H + h];
        accH += hx[i] * w;
        float v = rr[i] * w;
        accR += fabsf(v);
        errB[(size_t)(E_old + i) * H + h] = f2bf(v);
    }
    #pragma unroll 8
    for (int j = 0; j < H; ++j) accH += hh[j] * Whh[j * H + h];
    head_pre[b * H + h] = accH;
    rad[b * H + h] = accR;
}

// ---------------------------------------------------------------------------
// wprep (t>=1): per-sample WT[n][k] = bf16(lam[k]*WhhT[n][k]); analytic diag
// output rows err[diag_lo+r] = bf16(de[r]*Whh[r][:]) + rad contribution.
// grid (8, Bc), 256 thr; block s handles rows/cols [s*32, s*32+32).
// ---------------------------------------------------------------------------
__global__ __launch_bounds__(256) void wprep_k(
    const float* __restrict__ Whh, const float* __restrict__ WhhT32,
    const float* __restrict__ lam, const float* __restrict__ de,
    ushort_t* __restrict__ err, float* __restrict__ rad,
    ushort_t* __restrict__ WT, int diag_lo)
{
    __shared__ float de_c[32];
    const int s = blockIdx.x, b = blockIdx.y, h = threadIdx.x;
    if (h < 32) de_c[h] = de[b * H + s * 32 + h];
    float la = lam[b * H + h];
    __syncthreads();
    ushort_t* errB = err + (size_t)b * ESTRIDE * H;
    ushort_t* WTb  = WT + (size_t)b * H * H;
    #pragma unroll 4
    for (int i = 0; i < 32; ++i) {                       // WT rows n = s*32+i
        int n = s * 32 + i;
        WTb[(size_t)n * H + h] = f2bf(la * WhhT32[(size_t)n * H + h]);
    }
    float accR = 0.f;
    #pragma unroll 4
    for (int i = 0; i < 32; ++i) {                       // diag rows r = s*32+i
        int r = s * 32 + i;
        float v = de_c[i] * Whh[(size_t)r * H + h];
        errB[(size_t)(diag_lo + r) * H + h] = f2bf(v);
        accR += fabsf(v);
    }
    atomicAdd(&rad[b * H + h], accR);
}

// ---------------------------------------------------------------------------
// Main MFMA GEMM, IN PLACE: err[rows<nrows] <- err @ WT^T (WT = (lam*Whh)^T).
// Block = 128 rows x 256 cols (full width -> in-place safe), 4 waves,
// wave = 64 rows x 128 cols. A frags loaded DIRECTLY global->regs (err is
// frag-addressable bf16); B staged per K-quarter in padded LDS.
// rad[b,h] += sum_rows |C|. grid (ceil(nrows/128), Bc).
// ---------------------------------------------------------------------------
__global__ __launch_bounds__(256) void gemm_k(
    ushort_t* __restrict__ err, const ushort_t* __restrict__ WT,
    float* __restrict__ rad, int nrows)
{
    __shared__ ushort_t Bs[256 * 88];     // [n][k_quarter] pad->88 (45 KB)
    __shared__ float rad_s[H];
    const int b    = blockIdx.y;
    const int row0 = blockIdx.x * 128;
    const int tid  = threadIdx.x;
    const int wave = tid >> 6, lane = tid & 63;
    const int m = lane & 15, q = lane >> 4;
    const int rw = (wave >> 1) * 64;      // wave row offset
    const int cw = (wave & 1) * 128;      // wave col offset
    ushort_t* errB = err + (size_t)b * ESTRIDE * H;
    const ushort_t* WTb = WT + (size_t)b * H * H;

    rad_s[tid] = 0.f;

    f32x4 acc[4][8];
    #pragma unroll
    for (int i = 0; i < 4; ++i)
        #pragma unroll
        for (int c = 0; c < 8; ++c) acc[i][c] = (f32x4){0.f, 0.f, 0.f, 0.f};

    const ushort_t* aptr = errB + (size_t)(row0 + rw + m) * H + q * 8;

    for (int kq = 0; kq < 4; ++kq) {
        __syncthreads();
        {   // stage Bs: 256 n-rows x 64 k (128B/row), thread = n-row
            const ushort_t* src = WTb + (size_t)tid * H + kq * 64;
            ushort_t* dstp = &Bs[tid * 88];
            #pragma unroll
            for (int u = 0; u < 8; ++u)
                *(uint4*)(dstp + u * 8) = *(const uint4*)(src + u * 8);
        }
        __syncthreads();
        #pragma unroll
        for (int k2 = 0; k2 < 2; ++k2) {
            int kc = kq * 2 + k2;
            bf16x8 af[4];
            #pragma unroll
            for (int rt = 0; rt < 4; ++rt)
                af[rt] = *(const bf16x8*)(aptr + (size_t)rt * 16 * H + kc * 32);
            #pragma unroll
            for (int nt = 0; nt < 8; ++nt) {
                bf16x8 bf = *(const bf16x8*)&Bs[(cw + nt * 16 + m) * 88 + k2 * 32 + q * 8];
                #pragma unroll
                for (int rt = 0; rt < 4; ++rt)
                    acc[rt][nt] = __builtin_amdgcn_mfma_f32_16x16x32_bf16(
                        af[rt], bf, acc[rt][nt], 0, 0, 0);
            }
        }
    }

    // writeback (C/D: col = lane&15, row = q*4 + reg) + rad
    #pragma unroll
    for (int nt = 0; nt < 8; ++nt) {
        int col = cw + nt * 16 + m;
        float s = 0.f;
        #pragma unroll
        for (int rt = 0; rt < 4; ++rt) {
            int rbase = row0 + rw + rt * 16 + q * 4;
            #pragma unroll
            for (int r = 0; r < 4; ++r) {
                int row_g = rbase + r;
                if (row_g < nrows) {
                    float v = acc[rt][nt][r];
                    errB[(size_t)row_g * H + col] = f2bf(v);
                    s += fabsf(v);
                }
            }
        }
        atomicAdd(&rad_s[col], s);
    }
    __syncthreads();
    atomicAdd(&rad[b * H + tid], rad_s[tid]);
}

// ---------------------------------------------------------------------------
// final tanh: lam/de/head_h from (head_pre, rad). grid Bc x 256.
// ---------------------------------------------------------------------------
__global__ __launch_bounds__(256) void tanh_final_k(
    const float* __restrict__ head_pre, const float* __restrict__ rad,
    float* __restrict__ lam, float* __restrict__ de, float* __restrict__ head_h)
{
    const int b = blockIdx.x, h = threadIdx.x;
    float hd = head_pre[b * H + h], r = rad[b * H + h];
    float l = hd - r, u = hd + r;
    float tl = tanhf(l), tu = tanhf(u);
    float la = fminf(1.f - tl * tl, 1.f - tu * tu);
    float mu = 0.5f * (tu + tl - la * (u + l));
    float dd = 0.5f * (tu - tl - la * (u - l));
    lam[b * H + h] = la;
    de[b * H + h]  = dd;
    head_h[b * H + h] = la * hd + mu;
}

// ---------------------------------------------------------------------------
// pack WoT: WoTbf[b][n][k] = bf16(lam[k] * WoT32[n][k]). grid Bc x 256.
// ---------------------------------------------------------------------------
__global__ __launch_bounds__(256) void packWoT_k(
    const float* __restrict__ WoT32, const float* __restrict__ lam,
    ushort_t* __restrict__ WoTbf)
{
    const int b = blockIdx.x, k = threadIdx.x;
    float la = lam[b * H + k];
    ushort_t* dst = WoTbf + (size_t)b * N_OUT * H;
    #pragma unroll 4
    for (int n = 0; n < N_OUT; ++n)
        dst[(size_t)n * H + k] = f2bf(la * WoT32[(size_t)n * H + k]);
}

// ---------------------------------------------------------------------------
// head_out = head_h@Wo + bo ; rad_out init = sum_i |de[i]*Wo[i,:]| (final diag)
// grid Bc x 64
// ---------------------------------------------------------------------------
__global__ void head_out_k(
    const float* __restrict__ head_h, const float* __restrict__ de,
    const float* __restrict__ Wo, const float* __restrict__ bo,
    float* __restrict__ head_out, float* __restrict__ rad_out)
{
    const int b = blockIdx.x, o = threadIdx.x;
    float acc = bo[o], accR = 0.f;
    #pragma unroll 4
    for (int j = 0; j < H; ++j) {
        float w = Wo[j * N_OUT + o];
        acc  += head_h[b * H + j] * w;
        accR += fabsf(de[b * H + j] * w);
    }
    head_out[b * N_OUT + o] = acc;
    rad_out[b * N_OUT + o]  = accR;
}

// ---------------------------------------------------------------------------
// final radius via MFMA: rad_out[b,:] += sum_rows |err @ WoTbf^T| over all
// ESTRIDE rows (lam folded into WoTbf). Block 128 rows x 64 cols, 4 waves
// (wave 32x64). B staged whole-K once. grid (ESTRIDE/128, Bc).
// ---------------------------------------------------------------------------
__global__ __launch_bounds__(256) void gemm_out_k(
    const ushort_t* __restrict__ err, const ushort_t* __restrict__ WoTbf,
    float* __restrict__ rad_out)
{
    __shared__ ushort_t Bs[64 * 264];     // [n][k] pad 256->264 (33.8 KB)
    __shared__ float rad_s[N_OUT];
    const int b    = blockIdx.y;
    const int row0 = blockIdx.x * 128;
    const int tid  = threadIdx.x;
    const int wave = tid >> 6, lane = tid & 63;
    const int m = lane & 15, q = lane >> 4;
    const ushort_t* errB = err + (size_t)b * ESTRIDE * H;
    const ushort_t* Wb   = WoTbf + (size_t)b * N_OUT * H;

    if (tid < N_OUT) rad_s[tid] = 0.f;
    {   // stage B: 64 rows x 512B; thread = quarter-row
        int r = tid >> 2, qt = tid & 3;
        const ushort_t* src = Wb + (size_t)r * H + qt * 64;
        ushort_t* dstp = &Bs[r * 264 + qt * 64];
        #pragma unroll
        for (int u = 0; u < 8; ++u)
            *(uint4*)(dstp + u * 8) = *(const uint4*)(src + u * 8);
    }
    __syncthreads();

    f32x4 acc[2][4];
    #pragma unroll
    for (int i = 0; i < 2; ++i)
        #pragma unroll
        for (int c = 0; c < 4; ++c) acc[i][c] = (f32x4){0.f, 0.f, 0.f, 0.f};

    const ushort_t* aptr = errB + (size_t)(row0 + wave * 32 + m) * H + q * 8;
    #pragma unroll
    for (int kc = 0; kc < 8; ++kc) {
        bf16x8 af[2];
        #pragma unroll
        for (int rt = 0; rt < 2; ++rt)
            af[rt] = *(const bf16x8*)(aptr + (size_t)rt * 16 * H + kc * 32);
        #pragma unroll
        for (int nt = 0; nt < 4; ++nt) {
            bf16x8 bf = *(const bf16x8*)&Bs[(nt * 16 + m) * 264 + kc * 32 + q * 8];
            #pragma unroll
            for (int rt = 0; rt < 2; ++rt)
                acc[rt][nt] = __builtin_amdgcn_mfma_f32_16x16x32_bf16(
                    af[rt], bf, acc[rt][nt], 0, 0, 0);
        }
    }
    #pragma unroll
    for (int nt = 0; nt < 4; ++nt) {
        int col = nt * 16 + m;
        float s = 0.f;
        #pragma unroll
        for (int rt = 0; rt < 2; ++rt)
            #pragma unroll
            for (int r = 0; r < 4; ++r) s += fabsf(acc[rt][nt][r]);
        atomicAdd(&rad_s[col], s);
    }
    __syncthreads();
    if (tid < N_OUT) atomicAdd(&rad_out[b * N_OUT + tid], rad_s[tid]);
}

// ---------------------------------------------------------------------------
__global__ void combine_k(const float* __restrict__ head_out,
                          const float* __restrict__ rad_out,
                          float* __restrict__ out)
{
    int i = blockIdx.x * 256 + threadIdx.x;
    if (i < BSZ * N_OUT) {
        float h = head_out[i], r = rad_out[i];
        out[i]               = h - r;
        out[BSZ * N_OUT + i] = h + r;
    }
}

// ---------------------------------------------------------------------------
extern "C" void kernel_launch(void* const* d_in, const int* in_sizes, int n_in,
                              void* d_out, int out_size, void* d_ws, size_t ws_size,
                              hipStream_t stream)
{
    const float* X    = (const float*)d_in[0];
    const float* eps  = (const float*)d_in[1];
    const float* Wih  = (const float*)d_in[2];
    const float* Whh  = (const float*)d_in[3];
    const float* bih  = (const float*)d_in[4];
    const float* bhh  = (const float*)d_in[5];
    const float* Wo   = (const float*)d_in[6];
    const float* bo   = (const float*)d_in[7];
    float* out = (float*)d_out;

    // per-sample: err bf16 + WT bf16 + WoTbf
    const size_t per_sample = (size_t)ESTRIDE * H * 2 + (size_t)H * H * 2
                            + (size_t)N_OUT * H * 2;                  // 5.28 MB
    const size_t shared_b = (size_t)H * H * 4 + (size_t)N_OUT * H * 4
                          + (size_t)5 * BSZ * H * 4 + (size_t)2 * BSZ * N_OUT * 4 + 256;
    int Bc = BSZ;
    while (Bc > 1 && (size_t)Bc * per_sample + shared_b > ws_size) Bc >>= 1;

    char* p = (char*)d_ws;
    ushort_t* err    = (ushort_t*)p;  p += (size_t)Bc * ESTRIDE * H * 2;
    ushort_t* WT     = (ushort_t*)p;  p += (size_t)Bc * H * H * 2;
    ushort_t* WoTbf  = (ushort_t*)p;  p += (size_t)Bc * N_OUT * H * 2;
    float* WhhT32    = (float*)p;     p += (size_t)H * H * 4;
    float* WoT32     = (float*)p;     p += (size_t)N_OUT * H * 4;
    float* head_pre  = (float*)p;     p += (size_t)BSZ * H * 4;
    float* rad       = (float*)p;     p += (size_t)BSZ * H * 4;
    float* lam       = (float*)p;     p += (size_t)BSZ * H * 4;
    float* de        = (float*)p;     p += (size_t)BSZ * H * 4;
    float* head_h    = (float*)p;     p += (size_t)BSZ * H * 4;
    float* head_out  = (float*)p;     p += (size_t)BSZ * N_OUT * 4;
    float* rad_out   = (float*)p;

    transpose_k<<<dim3(H / 32, H / 32), 256, 0, stream>>>(Whh, WhhT32, H, H);
    transpose_k<<<dim3(N_OUT / 32, H / 32), 256, 0, stream>>>(Wo, WoT32, H, N_OUT);

    for (int b0 = 0; b0 < BSZ; b0 += Bc) {
        for (int t = 0; t < T_STEPS; ++t) {
            int E_old   = t * (N_IN + H);
            int diag_lo = E_old - H;
            prep_k<<<Bc, 256, 0, stream>>>(
                X + (size_t)(t * BSZ + b0) * N_IN, eps + b0, Wih, Whh, bih, bhh,
                head_pre + (size_t)b0 * H, rad + (size_t)b0 * H,
                lam + (size_t)b0 * H, de + (size_t)b0 * H,
                err, E_old, t == 0 ? 1 : 0);
            if (t >= 1) {
                wprep_k<<<dim3(8, Bc), 256, 0, stream>>>(
                    Whh, WhhT32, lam + (size_t)b0 * H, de + (size_t)b0 * H,
                    err, rad + (size_t)b0 * H, WT, diag_lo);
                gemm_k<<<dim3((diag_lo + 127) / 128, Bc), 256, 0, stream>>>(
                    err, WT, rad + (size_t)b0 * H, diag_lo);
            }
        }
        tanh_final_k<<<Bc, 256, 0, stream>>>(
            head_pre + (size_t)b0 * H, rad + (size_t)b0 * H,
            lam + (size_t)b0 * H, de + (size_t)b0 * H, head_h + (size_t)b0 * H);
        packWoT_k<<<Bc, 256, 0, stream>>>(WoT32, lam + (size_t)b0 * H, WoTbf);
        head_out_k<<<Bc, 64, 0, stream>>>(
            head_h + (size_t)b0 * H, de + (size_t)b0 * H, Wo, bo,
            head_out + (size_t)b0 * N_OUT, rad_out + (size_t)b0 * N_OUT);
        gemm_out_k<<<dim3(ESTRIDE / 128, Bc), 256, 0, stream>>>(
            err, WoTbf, rad_out + (size_t)b0 * N_OUT);
    }

    combine_k<<<(BSZ * N_OUT + 255) / 256, 256, 0, stream>>>(head_out, rad_out, out);
}

// Round 5
// 3358.448 us; speedup vs baseline: 3.3033x; 1.0607x over previous
//
#include <hip/hip_runtime.h>
#include <math.h>

typedef unsigned short ushort_t;
typedef __attribute__((ext_vector_type(8))) short bf16x8;   // MFMA A/B frag
typedef __attribute__((ext_vector_type(4))) float f32x4;    // MFMA C/D frag

#define T_STEPS 32
#define BSZ     32
#define N_IN    64
#define H       256
#define N_OUT   64
#define ESTRIDE 9984              // max materialized err rows = 320*31 + 64
#define CLAMP_MIN (-2.0f)
#define CLAMP_MAX ( 2.0f)

__device__ inline ushort_t f2bf(float x) {                  // RTNE fp32->bf16
    unsigned u = __builtin_bit_cast(unsigned, x);
    unsigned r = u + 0x7FFFu + ((u >> 16) & 1u);
    return (ushort_t)(r >> 16);
}

// ---------------------------------------------------------------------------
// One-time fp32 transpose: dst[C][R] = src[R][C]^T. grid (C/32, R/32), 256 thr
// ---------------------------------------------------------------------------
__global__ void transpose_k(const float* __restrict__ src, float* __restrict__ dst,
                            int R, int C)
{
    __shared__ float tile[32][33];
    int bi = blockIdx.y, bj = blockIdx.x;
    int r0 = threadIdx.x >> 5, c = threadIdx.x & 31;
    #pragma unroll
    for (int rr = 0; rr < 4; ++rr) {
        int r = r0 * 4 + rr;
        tile[r][c] = src[(bi * 32 + r) * C + bj * 32 + c];
    }
    __syncthreads();
    #pragma unroll
    for (int rr = 0; rr < 4; ++rr) {
        int r = r0 * 4 + rr;
        dst[(bj * 32 + r) * R + bi * 32 + c] = tile[c][r];
    }
}

// ---------------------------------------------------------------------------
// prep: (t>0) tanh of prev step -> lam/de/head_h(local); head_pre_t; fresh
// input-error rows [E_old, E_old+64) in bf16; rad init. grid Bc x 256.
// ---------------------------------------------------------------------------
__global__ __launch_bounds__(256) void prep_k(
    const float* __restrict__ Xt, const float* __restrict__ eps,
    const float* __restrict__ Wih, const float* __restrict__ Whh,
    const float* __restrict__ bih, const float* __restrict__ bhh,
    float* __restrict__ head_pre, float* __restrict__ rad,
    float* __restrict__ lam, float* __restrict__ de,
    ushort_t* __restrict__ err, int E_old, int is_t0)
{
    __shared__ float hx[N_IN], rr[N_IN], hh[H];
    const int b = blockIdx.x, h = threadIdx.x;
    float hh_val = 0.0f;
    if (!is_t0) {
        float hd = head_pre[b * H + h], r = rad[b * H + h];
        float l = hd - r, u = hd + r;
        float tl = tanhf(l), tu = tanhf(u);
        float la = fminf(1.f - tl * tl, 1.f - tu * tu);
        float mu = 0.5f * (tu + tl - la * (u + l));
        float dd = 0.5f * (tu - tl - la * (u - l));
        lam[b * H + h] = la;
        de[b * H + h]  = dd;
        hh_val = la * hd + mu;
    }
    hh[h] = hh_val;
    if (h < N_IN) {
        float x = Xt[b * N_IN + h], e = eps[b];
        float l = fmaxf(x - e, CLAMP_MIN);
        float u = fminf(x + e, CLAMP_MAX);
        hx[h] = 0.5f * (l + u);
        rr[h] = 0.5f * (u - l);
    }
    __syncthreads();
    float accH = bih[h] + bhh[h], accR = 0.f;
    ushort_t* errB = err + (size_t)b * ESTRIDE * H;
    #pragma unroll 8
    for (int i = 0; i < N_IN; ++i) {
        float w = Wih[i * H + h];
        accH += hx[i] * w;
        float v = rr[i] * w;
        accR += fabsf(v);
        errB[(size_t)(E_old + i) * H + h] = f2bf(v);
    }
    #pragma unroll 8
    for (int j = 0; j < H; ++j) accH += hh[j] * Whh[j * H + h];
    head_pre[b * H + h] = accH;
    rad[b * H + h] = accR;
}

// ---------------------------------------------------------------------------
// wprep (t>=1): per-sample WT[n][k] = bf16(lam[k]*WhhT[n][k]); analytic diag
// output rows err[diag_lo+r] = bf16(de[r]*Whh[r][:]) + rad contribution.
// grid (8, Bc), 256 thr; block s handles rows/cols [s*32, s*32+32).
// ---------------------------------------------------------------------------
__global__ __launch_bounds__(256) void wprep_k(
    const float* __restrict__ Whh, const float* __restrict__ WhhT32,
    const float* __restrict__ lam, const float* __restrict__ de,
    ushort_t* __restrict__ err, float* __restrict__ rad,
    ushort_t* __restrict__ WT, int diag_lo)
{
    __shared__ float de_c[32];
    const int s = blockIdx.x, b = blockIdx.y, h = threadIdx.x;
    if (h < 32) de_c[h] = de[b * H + s * 32 + h];
    float la = lam[b * H + h];
    __syncthreads();
    ushort_t* errB = err + (size_t)b * ESTRIDE * H;
    ushort_t* WTb  = WT + (size_t)b * H * H;
    #pragma unroll 4
    for (int i = 0; i < 32; ++i) {                       // WT rows n = s*32+i
        int n = s * 32 + i;
        WTb[(size_t)n * H + h] = f2bf(la * WhhT32[(size_t)n * H + h]);
    }
    float accR = 0.f;
    #pragma unroll 4
    for (int i = 0; i < 32; ++i) {                       // diag rows r = s*32+i
        int r = s * 32 + i;
        float v = de_c[i] * Whh[(size_t)r * H + h];
        errB[(size_t)(diag_lo + r) * H + h] = f2bf(v);
        accR += fabsf(v);
    }
    atomicAdd(&rad[b * H + h], accR);
}

// ---------------------------------------------------------------------------
// Main MFMA GEMM, IN PLACE, barrier-free K-loop:
//   err[0..nrows) <- err @ WT^T   (WT = (lam*Whh)^T, per-sample bf16)
// Block = 64 rows x 256 cols (full width -> in-place safe), 4 waves, each
// wave a 64x64 tile. A and B fragments both load DIRECTLY global->regs
// (err rows are frag-addressable; WT per-kc slice is 16 KB, L1-resident).
// K fully unrolled; one __syncthreads between last read and in-place write.
// rad[b,h] += sum_rows |C|. grid (nrows/64, Bc). nrows % 64 == 0.
// ---------------------------------------------------------------------------
__global__ __launch_bounds__(256) void gemm_k(
    ushort_t* __restrict__ err, const ushort_t* __restrict__ WT,
    float* __restrict__ rad, int nrows)
{
    __shared__ float rad_s[H];
    const int b    = blockIdx.y;
    const int row0 = blockIdx.x * 64;
    const int tid  = threadIdx.x;
    const int wave = tid >> 6, lane = tid & 63;
    const int m = lane & 15, q = lane >> 4;
    ushort_t* errB = err + (size_t)b * ESTRIDE * H;
    const ushort_t* WTb = WT + (size_t)b * H * H;

    rad_s[tid] = 0.f;

    f32x4 acc[4][4];                      // [rt][nt]
    #pragma unroll
    for (int i = 0; i < 4; ++i)
        #pragma unroll
        for (int c = 0; c < 4; ++c) acc[i][c] = (f32x4){0.f, 0.f, 0.f, 0.f};

    // A frag: row = row0 + rt*16 + m, k = kc*32 + q*8 + j
    // B frag: n   = wave*64 + nt*16 + m, same k
    const ushort_t* aptr = errB + (size_t)(row0 + m) * H + q * 8;
    const ushort_t* bptr = WTb + (size_t)(wave * 64 + m) * H + q * 8;

    #pragma unroll
    for (int kc = 0; kc < 8; ++kc) {
        bf16x8 af[4], bf[4];
        #pragma unroll
        for (int rt = 0; rt < 4; ++rt)
            af[rt] = *(const bf16x8*)(aptr + (size_t)rt * 16 * H + kc * 32);
        #pragma unroll
        for (int nt = 0; nt < 4; ++nt)
            bf[nt] = *(const bf16x8*)(bptr + (size_t)nt * 16 * H + kc * 32);
        #pragma unroll
        for (int nt = 0; nt < 4; ++nt)
            #pragma unroll
            for (int rt = 0; rt < 4; ++rt)
                acc[rt][nt] = __builtin_amdgcn_mfma_f32_16x16x32_bf16(
                    af[rt], bf[nt], acc[rt][nt], 0, 0, 0);
    }

    __syncthreads();   // all waves' K-reads drained before in-place writes

    // writeback (C/D: col = lane&15 within 16, row = q*4 + reg) + rad
    #pragma unroll
    for (int nt = 0; nt < 4; ++nt) {
        int col = wave * 64 + nt * 16 + m;
        float s = 0.f;
        #pragma unroll
        for (int rt = 0; rt < 4; ++rt) {
            int rbase = row0 + rt * 16 + q * 4;
            #pragma unroll
            for (int r = 0; r < 4; ++r) {
                float v = acc[rt][nt][r];
                errB[(size_t)(rbase + r) * H + col] = f2bf(v);
                s += fabsf(v);
            }
        }
        atomicAdd(&rad_s[col], s);
    }
    __syncthreads();
    atomicAdd(&rad[b * H + tid], rad_s[tid]);
}

// ---------------------------------------------------------------------------
// final tanh: lam/de/head_h from (head_pre, rad). grid Bc x 256.
// ---------------------------------------------------------------------------
__global__ __launch_bounds__(256) void tanh_final_k(
    const float* __restrict__ head_pre, const float* __restrict__ rad,
    float* __restrict__ lam, float* __restrict__ de, float* __restrict__ head_h)
{
    const int b = blockIdx.x, h = threadIdx.x;
    float hd = head_pre[b * H + h], r = rad[b * H + h];
    float l = hd - r, u = hd + r;
    float tl = tanhf(l), tu = tanhf(u);
    float la = fminf(1.f - tl * tl, 1.f - tu * tu);
    float mu = 0.5f * (tu + tl - la * (u + l));
    float dd = 0.5f * (tu - tl - la * (u - l));
    lam[b * H + h] = la;
    de[b * H + h]  = dd;
    head_h[b * H + h] = la * hd + mu;
}

// ---------------------------------------------------------------------------
// pack WoT: WoTbf[b][n][k] = bf16(lam[k] * WoT32[n][k]). grid Bc x 256.
// ---------------------------------------------------------------------------
__global__ __launch_bounds__(256) void packWoT_k(
    const float* __restrict__ WoT32, const float* __restrict__ lam,
    ushort_t* __restrict__ WoTbf)
{
    const int b = blockIdx.x, k = threadIdx.x;
    float la = lam[b * H + k];
    ushort_t* dst = WoTbf + (size_t)b * N_OUT * H;
    #pragma unroll 4
    for (int n = 0; n < N_OUT; ++n)
        dst[(size_t)n * H + k] = f2bf(la * WoT32[(size_t)n * H + k]);
}

// ---------------------------------------------------------------------------
// head_out = head_h@Wo + bo ; rad_out init = sum_i |de[i]*Wo[i,:]| (final diag)
// grid Bc x 64
// ---------------------------------------------------------------------------
__global__ void head_out_k(
    const float* __restrict__ head_h, const float* __restrict__ de,
    const float* __restrict__ Wo, const float* __restrict__ bo,
    float* __restrict__ head_out, float* __restrict__ rad_out)
{
    const int b = blockIdx.x, o = threadIdx.x;
    float acc = bo[o], accR = 0.f;
    #pragma unroll 4
    for (int j = 0; j < H; ++j) {
        float w = Wo[j * N_OUT + o];
        acc  += head_h[b * H + j] * w;
        accR += fabsf(de[b * H + j] * w);
    }
    head_out[b * N_OUT + o] = acc;
    rad_out[b * N_OUT + o]  = accR;
}

// ---------------------------------------------------------------------------
// final radius via MFMA: rad_out[b,:] += sum_rows |err @ WoTbf^T| over all
// ESTRIDE rows (lam folded into WoTbf). Block 128 rows x 64 cols, 4 waves
// (wave 32x64). B staged whole-K once. grid (ESTRIDE/128, Bc).
// ---------------------------------------------------------------------------
__global__ __launch_bounds__(256) void gemm_out_k(
    const ushort_t* __restrict__ err, const ushort_t* __restrict__ WoTbf,
    float* __restrict__ rad_out)
{
    __shared__ ushort_t Bs[64 * 264];     // [n][k] pad 256->264 (33.8 KB)
    __shared__ float rad_s[N_OUT];
    const int b    = blockIdx.y;
    const int row0 = blockIdx.x * 128;
    const int tid  = threadIdx.x;
    const int wave = tid >> 6, lane = tid & 63;
    const int m = lane & 15, q = lane >> 4;
    const ushort_t* errB = err + (size_t)b * ESTRIDE * H;
    const ushort_t* Wb   = WoTbf + (size_t)b * N_OUT * H;

    if (tid < N_OUT) rad_s[tid] = 0.f;
    {   // stage B: 64 rows x 512B; thread = quarter-row
        int r = tid >> 2, qt = tid & 3;
        const ushort_t* src = Wb + (size_t)r * H + qt * 64;
        ushort_t* dstp = &Bs[r * 264 + qt * 64];
        #pragma unroll
        for (int u = 0; u < 8; ++u)
            *(uint4*)(dstp + u * 8) = *(const uint4*)(src + u * 8);
    }
    __syncthreads();

    f32x4 acc[2][4];
    #pragma unroll
    for (int i = 0; i < 2; ++i)
        #pragma unroll
        for (int c = 0; c < 4; ++c) acc[i][c] = (f32x4){0.f, 0.f, 0.f, 0.f};

    const ushort_t* aptr = errB + (size_t)(row0 + wave * 32 + m) * H + q * 8;
    #pragma unroll
    for (int kc = 0; kc < 8; ++kc) {
        bf16x8 af[2];
        #pragma unroll
        for (int rt = 0; rt < 2; ++rt)
            af[rt] = *(const bf16x8*)(aptr + (size_t)rt * 16 * H + kc * 32);
        #pragma unroll
        for (int nt = 0; nt < 4; ++nt) {
            bf16x8 bf = *(const bf16x8*)&Bs[(nt * 16 + m) * 264 + kc * 32 + q * 8];
            #pragma unroll
            for (int rt = 0; rt < 2; ++rt)
                acc[rt][nt] = __builtin_amdgcn_mfma_f32_16x16x32_bf16(
                    af[rt], bf, acc[rt][nt], 0, 0, 0);
        }
    }
    #pragma unroll
    for (int nt = 0; nt < 4; ++nt) {
        int col = nt * 16 + m;
        float s = 0.f;
        #pragma unroll
        for (int rt = 0; rt < 2; ++rt)
            #pragma unroll
            for (int r = 0; r < 4; ++r) s += fabsf(acc[rt][nt][r]);
        atomicAdd(&rad_s[col], s);
    }
    __syncthreads();
    if (tid < N_OUT) atomicAdd(&rad_out[b * N_OUT + tid], rad_s[tid]);
}

// ---------------------------------------------------------------------------
__global__ void combine_k(const float* __restrict__ head_out,
                          const float* __restrict__ rad_out,
                          float* __restrict__ out)
{
    int i = blockIdx.x * 256 + threadIdx.x;
    if (i < BSZ * N_OUT) {
        float h = head_out[i], r = rad_out[i];
        out[i]               = h - r;
        out[BSZ * N_OUT + i] = h + r;
    }
}

// ---------------------------------------------------------------------------
extern "C" void kernel_launch(void* const* d_in, const int* in_sizes, int n_in,
                              void* d_out, int out_size, void* d_ws, size_t ws_size,
                              hipStream_t stream)
{
    const float* X    = (const float*)d_in[0];
    const float* eps  = (const float*)d_in[1];
    const float* Wih  = (const float*)d_in[2];
    const float* Whh  = (const float*)d_in[3];
    const float* bih  = (const float*)d_in[4];
    const float* bhh  = (const float*)d_in[5];
    const float* Wo   = (const float*)d_in[6];
    const float* bo   = (const float*)d_in[7];
    float* out = (float*)d_out;

    // per-sample: err bf16 + WT bf16 + WoTbf
    const size_t per_sample = (size_t)ESTRIDE * H * 2 + (size_t)H * H * 2
                            + (size_t)N_OUT * H * 2;                  // 5.28 MB
    const size_t shared_b = (size_t)H * H * 4 + (size_t)N_OUT * H * 4
                          + (size_t)5 * BSZ * H * 4 + (size_t)2 * BSZ * N_OUT * 4 + 256;
    int Bc = BSZ;
    while (Bc > 1 && (size_t)Bc * per_sample + shared_b > ws_size) Bc >>= 1;

    char* p = (char*)d_ws;
    ushort_t* err    = (ushort_t*)p;  p += (size_t)Bc * ESTRIDE * H * 2;
    ushort_t* WT     = (ushort_t*)p;  p += (size_t)Bc * H * H * 2;
    ushort_t* WoTbf  = (ushort_t*)p;  p += (size_t)Bc * N_OUT * H * 2;
    float* WhhT32    = (float*)p;     p += (size_t)H * H * 4;
    float* WoT32     = (float*)p;     p += (size_t)N_OUT * H * 4;
    float* head_pre  = (float*)p;     p += (size_t)BSZ * H * 4;
    float* rad       = (float*)p;     p += (size_t)BSZ * H * 4;
    float* lam       = (float*)p;     p += (size_t)BSZ * H * 4;
    float* de        = (float*)p;     p += (size_t)BSZ * H * 4;
    float* head_h    = (float*)p;     p += (size_t)BSZ * H * 4;
    float* head_out  = (float*)p;     p += (size_t)BSZ * N_OUT * 4;
    float* rad_out   = (float*)p;

    transpose_k<<<dim3(H / 32, H / 32), 256, 0, stream>>>(Whh, WhhT32, H, H);
    transpose_k<<<dim3(N_OUT / 32, H / 32), 256, 0, stream>>>(Wo, WoT32, H, N_OUT);

    for (int b0 = 0; b0 < BSZ; b0 += Bc) {
        for (int t = 0; t < T_STEPS; ++t) {
            int E_old   = t * (N_IN + H);
            int diag_lo = E_old - H;
            prep_k<<<Bc, 256, 0, stream>>>(
                X + (size_t)(t * BSZ + b0) * N_IN, eps + b0, Wih, Whh, bih, bhh,
                head_pre + (size_t)b0 * H, rad + (size_t)b0 * H,
                lam + (size_t)b0 * H, de + (size_t)b0 * H,
                err, E_old, t == 0 ? 1 : 0);
            if (t >= 1) {
                wprep_k<<<dim3(8, Bc), 256, 0, stream>>>(
                    Whh, WhhT32, lam + (size_t)b0 * H, de + (size_t)b0 * H,
                    err, rad + (size_t)b0 * H, WT, diag_lo);
                gemm_k<<<dim3(diag_lo / 64, Bc), 256, 0, stream>>>(
                    err, WT, rad + (size_t)b0 * H, diag_lo);
            }
        }
        tanh_final_k<<<Bc, 256, 0, stream>>>(
            head_pre + (size_t)b0 * H, rad + (size_t)b0 * H,
            lam + (size_t)b0 * H, de + (size_t)b0 * H, head_h + (size_t)b0 * H);
        packWoT_k<<<Bc, 256, 0, stream>>>(WoT32, lam + (size_t)b0 * H, WoTbf);
        head_out_k<<<Bc, 64, 0, stream>>>(
            head_h + (size_t)b0 * H, de + (size_t)b0 * H, Wo, bo,
            head_out + (size_t)b0 * N_OUT, rad_out + (size_t)b0 * N_OUT);
        gemm_out_k<<<dim3(ESTRIDE / 128, Bc), 256, 0, stream>>>(
            err, WoTbf, rad_out + (size_t)b0 * N_OUT);
    }

    combine_k<<<(BSZ * N_OUT + 255) / 256, 256, 0, stream>>>(head_out, rad_out, out);
}

// Round 6
// 2724.758 us; speedup vs baseline: 4.0715x; 1.2326x over previous
//
#include <hip/hip_runtime.h>
#include <math.h>

typedef unsigned short u16;
typedef __attribute__((ext_vector_type(8))) short bf16x8;   // MFMA A/B frag
typedef __attribute__((ext_vector_type(4))) float f32x4;    // MFMA C/D frag

#define T_STEPS 32
#define BSZ     32
#define N_IN    64
#define H       256
#define N_OUT   64
#define ESTRIDE 9984              // rows = 320*31 + 64 (final fresh block)
#define CLAMP_MIN (-2.0f)
#define CLAMP_MAX ( 2.0f)

// Fragment-packed layout: chunk = (row>>4)*8 + (k>>5), 512 u16 per chunk,
// within-chunk elem = (((k&31)>>3)*16 + (row&15))*8 + (k&7)
// => A-frag load for (tile,kc) is base + chunk*512 + lane*8, 16B/lane coalesced.

__device__ inline u16 f2bf(float x) {                       // RTNE fp32->bf16
    unsigned u = __builtin_bit_cast(unsigned, x);
    unsigned r = u + 0x7FFFu + ((u >> 16) & 1u);
    return (u16)(r >> 16);
}

// ---------------------------------------------------------------------------
__global__ void init_k(float* __restrict__ radT) {          // zero [T][B][H]
    int i = blockIdx.x * 256 + threadIdx.x;
    radT[i] = 0.0f;
}

// ---------------------------------------------------------------------------
__global__ void transpose_k(const float* __restrict__ src, float* __restrict__ dst,
                            int R, int C)
{
    __shared__ float tile[32][33];
    int bi = blockIdx.y, bj = blockIdx.x;
    int r0 = threadIdx.x >> 5, c = threadIdx.x & 31;
    #pragma unroll
    for (int rr = 0; rr < 4; ++rr) {
        int r = r0 * 4 + rr;
        tile[r][c] = src[(bi * 32 + r) * C + bj * 32 + c];
    }
    __syncthreads();
    #pragma unroll
    for (int rr = 0; rr < 4; ++rr) {
        int r = r0 * 4 + rr;
        dst[(bj * 32 + r) * R + bi * 32 + c] = tile[c][r];
    }
}

// ---------------------------------------------------------------------------
// prep0: head_pre_0, fresh rows [0,64) frag-packed, rad[0]. grid Bc x 256.
// ---------------------------------------------------------------------------
__global__ __launch_bounds__(256) void prep0_k(
    const float* __restrict__ X0, const float* __restrict__ eps,
    const float* __restrict__ Wih, const float* __restrict__ bih,
    const float* __restrict__ bhh,
    float* __restrict__ hp0, float* __restrict__ rad0, u16* __restrict__ err)
{
    __shared__ float hx[N_IN], rr[N_IN], rad_s[H];
    const int b = blockIdx.x, tid = threadIdx.x;
    if (tid < N_IN) {
        float x = X0[b * N_IN + tid], e = eps[b];
        float l = fmaxf(x - e, CLAMP_MIN), u = fminf(x + e, CLAMP_MAX);
        hx[tid] = 0.5f * (l + u);
        rr[tid] = 0.5f * (u - l);
    }
    rad_s[tid] = 0.f;
    __syncthreads();

    float acc = bih[tid] + bhh[tid];
    #pragma unroll 8
    for (int i = 0; i < N_IN; ++i) acc += hx[i] * Wih[i * H + tid];
    hp0[b * H + tid] = acc;

    u16* errB = err + (size_t)b * ESTRIDE * H;
    const int e = tid * 2, q = e >> 7, m = (e >> 3) & 15, j = e & 7;
    #pragma unroll
    for (int ti = 0; ti < 4; ++ti) {
        int i = ti * 16 + m;                 // fresh-row index 0..63
        float rho = rr[i];
        #pragma unroll
        for (int kc = 0; kc < 8; ++kc) {
            int k = kc * 32 + q * 8 + j;
            float v0 = rho * Wih[(size_t)i * H + k];
            float v1 = rho * Wih[(size_t)i * H + k + 1];
            unsigned pk = (unsigned)f2bf(v0) | ((unsigned)f2bf(v1) << 16);
            *(unsigned*)&errB[(size_t)(ti * 8 + kc) * 512 + e] = pk;
            atomicAdd(&rad_s[k], fabsf(v0));
            atomicAdd(&rad_s[k + 1], fabsf(v1));
        }
    }
    __syncthreads();
    atomicAdd(&rad0[b * H + tid], rad_s[tid]);
}

// ---------------------------------------------------------------------------
// mid_k (t>=1): fused tanh(prev) + WT pack + diag rows + fresh rows + head GEMV.
// grid (10, Bc), 256 thr. roles: 0..7 = WT/diag slice, 8 = head, 9 = fresh.
// ---------------------------------------------------------------------------
__global__ __launch_bounds__(256) void mid_k(
    const float* __restrict__ Xt, const float* __restrict__ eps,
    const float* __restrict__ Wih, const float* __restrict__ Whh,
    const float* __restrict__ WhhT32,
    const float* __restrict__ bih, const float* __restrict__ bhh,
    const float* __restrict__ hp_prev, const float* __restrict__ rad_prev,
    float* __restrict__ hp_new, float* __restrict__ rad_new,
    u16* __restrict__ err, u16* __restrict__ WTp, int E_old)
{
    __shared__ float lam_s[H], de_s[H], aux_s[H], hxr[N_IN];
    const int role = blockIdx.x, b = blockIdx.y, tid = threadIdx.x;

    float hd = hp_prev[b * H + tid], r = rad_prev[b * H + tid];
    float l = hd - r, u = hd + r;
    float tl = tanhf(l), tu = tanhf(u);
    float la = fminf(1.f - tl * tl, 1.f - tu * tu);
    float mu = 0.5f * (tu + tl - la * (u + l));
    float dd = 0.5f * (tu - tl - la * (u - l));
    lam_s[tid] = la;
    de_s[tid]  = dd;
    aux_s[tid] = (role == 8) ? (la * hd + mu) : 0.f;   // hh for role 8, rad acc else
    if (tid < N_IN && role >= 8) {
        float x = Xt[b * N_IN + tid], e = eps[b];
        float lo = fmaxf(x - e, CLAMP_MIN), up = fminf(x + e, CLAMP_MAX);
        hxr[tid] = (role == 8) ? 0.5f * (lo + up) : 0.5f * (up - lo);
    }
    __syncthreads();

    if (role == 8) {
        float acc = bih[tid] + bhh[tid];
        #pragma unroll 8
        for (int i = 0; i < N_IN; ++i) acc += hxr[i] * Wih[i * H + tid];
        #pragma unroll 8
        for (int jj = 0; jj < H; ++jj) acc += aux_s[jj] * Whh[jj * H + tid];
        hp_new[b * H + tid] = acc;
        return;
    }

    u16* errB = err + (size_t)b * ESTRIDE * H;
    const int e = tid * 2, q = e >> 7, m = (e >> 3) & 15, j = e & 7;

    if (role < 8) {                            // WT slice + diag rows
        const int s = role;
        const int diag_lo = E_old - H;
        u16* WTb = WTp + (size_t)b * H * H;
        #pragma unroll
        for (int ti = 0; ti < 2; ++ti) {
            int nbase = (2 * s + ti) * 16 + m;       // WT n-row
            int rsrc  = s * 32 + ti * 16 + m;        // diag source index
            float dv  = de_s[rsrc];
            #pragma unroll
            for (int kc = 0; kc < 8; ++kc) {
                int k = kc * 32 + q * 8 + j;
                float w0 = WhhT32[(size_t)nbase * H + k];
                float w1 = WhhT32[(size_t)nbase * H + k + 1];
                unsigned pw = (unsigned)f2bf(lam_s[k] * w0)
                            | ((unsigned)f2bf(lam_s[k + 1] * w1) << 16);
                *(unsigned*)&WTb[(size_t)((2 * s + ti) * 8 + kc) * 512 + e] = pw;
                float v0 = dv * Whh[(size_t)rsrc * H + k];
                float v1 = dv * Whh[(size_t)rsrc * H + k + 1];
                unsigned pv = (unsigned)f2bf(v0) | ((unsigned)f2bf(v1) << 16);
                *(unsigned*)&errB[(size_t)(((diag_lo >> 4) + 2 * s + ti) * 8 + kc) * 512 + e] = pv;
                atomicAdd(&aux_s[k], fabsf(v0));
                atomicAdd(&aux_s[k + 1], fabsf(v1));
            }
        }
    } else {                                   // role 9: fresh rows
        #pragma unroll
        for (int ti = 0; ti < 4; ++ti) {
            int i = ti * 16 + m;
            float rho = hxr[i];
            #pragma unroll
            for (int kc = 0; kc < 8; ++kc) {
                int k = kc * 32 + q * 8 + j;
                float v0 = rho * Wih[(size_t)i * H + k];
                float v1 = rho * Wih[(size_t)i * H + k + 1];
                unsigned pv = (unsigned)f2bf(v0) | ((unsigned)f2bf(v1) << 16);
                *(unsigned*)&errB[(size_t)(((E_old >> 4) + ti) * 8 + kc) * 512 + e] = pv;
                atomicAdd(&aux_s[k], fabsf(v0));
                atomicAdd(&aux_s[k + 1], fabsf(v1));
            }
        }
    }
    __syncthreads();
    atomicAdd(&rad_new[b * H + tid], aux_s[tid]);
}

// ---------------------------------------------------------------------------
// Main MFMA GEMM, in place, frag-packed: err[0..nrows) <- err @ WT^T.
// Block 64 rows x 256 cols, 4 waves (wave 64x64). A staged to LDS (contiguous
// 32 KB copy), B frag loads direct (1KB coalesced). Writeback via wave-local
// LDS transform (C-layout -> A-frag layout) then full-line stores.
// grid (nrows/64, Bc).
// ---------------------------------------------------------------------------
__global__ __launch_bounds__(256) void gemm_k(
    u16* __restrict__ err, const u16* __restrict__ WTp,
    float* __restrict__ rad_new, int nrows)
{
    __shared__ u16 As[4 * 8 * 512];        // 32 KB; reused as transform buffer
    __shared__ float rad_s[H];
    const int b = blockIdx.y, row0 = blockIdx.x * 64, tid = threadIdx.x;
    const int wave = tid >> 6, lane = tid & 63;
    const int m = lane & 15, q = lane >> 4;
    u16* errB = err + (size_t)b * ESTRIDE * H;
    const u16* WTb = WTp + (size_t)b * H * H;

    rad_s[tid] = 0.f;
    {   // stage A: 32 KB contiguous (chunks (row0>>4)*8 .. +32)
        const u16* src = errB + (size_t)(row0 >> 4) * 4096;
        int off = tid * 8;
        #pragma unroll
        for (int it = 0; it < 8; ++it) {
            *(uint4*)&As[off] = *(const uint4*)&src[off];
            off += 256 * 8;
        }
    }
    __syncthreads();

    f32x4 acc[4][4];
    #pragma unroll
    for (int i = 0; i < 4; ++i)
        #pragma unroll
        for (int c = 0; c < 4; ++c) acc[i][c] = (f32x4){0.f, 0.f, 0.f, 0.f};

    #pragma unroll
    for (int kc = 0; kc < 8; ++kc) {
        bf16x8 af[4], bf[4];
        #pragma unroll
        for (int rt = 0; rt < 4; ++rt)
            af[rt] = *(const bf16x8*)&As[(rt * 8 + kc) * 512 + lane * 8];
        #pragma unroll
        for (int nt = 0; nt < 4; ++nt)
            bf[nt] = *(const bf16x8*)&WTb[(size_t)((wave * 4 + nt) * 8 + kc) * 512 + lane * 8];
        #pragma unroll
        for (int nt = 0; nt < 4; ++nt)
            #pragma unroll
            for (int rt = 0; rt < 4; ++rt)
                acc[rt][nt] = __builtin_amdgcn_mfma_f32_16x16x32_bf16(
                    af[rt], bf[nt], acc[rt][nt], 0, 0, 0);
    }
    __syncthreads();     // all waves done reading As before reuse

    // transform C (col=lane&15, row=q*4+reg) -> A-frag layout in wave region
    u16* W_ = &As[wave * 4096];
    #pragma unroll
    for (int nt = 0; nt < 4; ++nt) {
        int c32 = (nt & 1) * 16 + m;         // k within 32-chunk
        int q_a = c32 >> 3, jj = c32 & 7, kcl = nt >> 1;
        float s = 0.f;
        #pragma unroll
        for (int rt = 0; rt < 4; ++rt)
            #pragma unroll
            for (int r = 0; r < 4; ++r) {
                float v = acc[rt][nt][r];
                s += fabsf(v);
                W_[rt * 1024 + kcl * 512 + (q_a * 16 + q * 4 + r) * 8 + jj] = f2bf(v);
            }
        atomicAdd(&rad_s[wave * 64 + nt * 16 + m], s);
    }
    __syncthreads();     // LDS writes visible (+ rad_s complete)

    const int tile0 = row0 >> 4;
    #pragma unroll
    for (int rt = 0; rt < 4; ++rt)
        #pragma unroll
        for (int kcl = 0; kcl < 2; ++kcl) {
            uint4 v = *(uint4*)&W_[rt * 1024 + kcl * 512 + lane * 8];
            *(uint4*)&errB[(size_t)((tile0 + rt) * 8 + wave * 2 + kcl) * 512 + lane * 8] = v;
        }
    atomicAdd(&rad_new[b * H + tid], rad_s[tid]);
}

// ---------------------------------------------------------------------------
__global__ __launch_bounds__(256) void tanh_final_k(
    const float* __restrict__ hp, const float* __restrict__ rad,
    float* __restrict__ lam, float* __restrict__ de, float* __restrict__ head_h)
{
    const int b = blockIdx.x, h = threadIdx.x;
    float hd = hp[b * H + h], r = rad[b * H + h];
    float l = hd - r, u = hd + r;
    float tl = tanhf(l), tu = tanhf(u);
    float la = fminf(1.f - tl * tl, 1.f - tu * tu);
    float mu = 0.5f * (tu + tl - la * (u + l));
    float dd = 0.5f * (tu - tl - la * (u - l));
    lam[b * H + h] = la;
    de[b * H + h]  = dd;
    head_h[b * H + h] = la * hd + mu;
}

// ---------------------------------------------------------------------------
// pack WoT frag-packed, lam folded. grid Bc x 256.
// ---------------------------------------------------------------------------
__global__ __launch_bounds__(256) void packWoT_k(
    const float* __restrict__ WoT32, const float* __restrict__ lam,
    u16* __restrict__ WoTp)
{
    const int b = blockIdx.x, tid = threadIdx.x;
    __shared__ float lam_s[H];
    lam_s[tid] = lam[b * H + tid];
    __syncthreads();
    u16* dst = WoTp + (size_t)b * N_OUT * H;
    const int e = tid * 2, q = e >> 7, m = (e >> 3) & 15, j = e & 7;
    #pragma unroll
    for (int nt = 0; nt < 4; ++nt) {
        int n = nt * 16 + m;
        #pragma unroll
        for (int kc = 0; kc < 8; ++kc) {
            int k = kc * 32 + q * 8 + j;
            unsigned pw = (unsigned)f2bf(lam_s[k] * WoT32[(size_t)n * H + k])
                        | ((unsigned)f2bf(lam_s[k + 1] * WoT32[(size_t)n * H + k + 1]) << 16);
            *(unsigned*)&dst[(size_t)(nt * 8 + kc) * 512 + e] = pw;
        }
    }
}

// ---------------------------------------------------------------------------
__global__ void head_out_k(
    const float* __restrict__ head_h, const float* __restrict__ de,
    const float* __restrict__ Wo, const float* __restrict__ bo,
    float* __restrict__ head_out, float* __restrict__ rad_out)
{
    const int b = blockIdx.x, o = threadIdx.x;
    float acc = bo[o], accR = 0.f;
    #pragma unroll 4
    for (int j = 0; j < H; ++j) {
        float w = Wo[j * N_OUT + o];
        acc  += head_h[b * H + j] * w;
        accR += fabsf(de[b * H + j] * w);
    }
    head_out[b * N_OUT + o] = acc;
    rad_out[b * N_OUT + o]  = accR;
}

// ---------------------------------------------------------------------------
// final radius: rad_out += sum_rows |err @ WoTp^T| over all ESTRIDE rows.
// Block 256 rows x 64 cols, 4 waves (wave 64x64). grid (ESTRIDE/256, Bc).
// ---------------------------------------------------------------------------
__global__ __launch_bounds__(256) void gemm_out_k(
    const u16* __restrict__ err, const u16* __restrict__ WoTp,
    float* __restrict__ rad_out)
{
    __shared__ float rad_s[N_OUT];
    const int b = blockIdx.y, row0 = blockIdx.x * 256, tid = threadIdx.x;
    const int wave = tid >> 6, lane = tid & 63;
    const int m = lane & 15;
    const u16* errB = err + (size_t)b * ESTRIDE * H;
    const u16* Wb   = WoTp + (size_t)b * N_OUT * H;

    if (tid < N_OUT) rad_s[tid] = 0.f;
    __syncthreads();

    f32x4 acc[4][4];
    #pragma unroll
    for (int i = 0; i < 4; ++i)
        #pragma unroll
        for (int c = 0; c < 4; ++c) acc[i][c] = (f32x4){0.f, 0.f, 0.f, 0.f};

    const int tile0 = (row0 >> 4) + wave * 4;
    #pragma unroll
    for (int kc = 0; kc < 8; ++kc) {
        bf16x8 af[4], bf[4];
        #pragma unroll
        for (int rt = 0; rt < 4; ++rt)
            af[rt] = *(const bf16x8*)&errB[(size_t)((tile0 + rt) * 8 + kc) * 512 + lane * 8];
        #pragma unroll
        for (int nt = 0; nt < 4; ++nt)
            bf[nt] = *(const bf16x8*)&Wb[(size_t)(nt * 8 + kc) * 512 + lane * 8];
        #pragma unroll
        for (int nt = 0; nt < 4; ++nt)
            #pragma unroll
            for (int rt = 0; rt < 4; ++rt)
                acc[rt][nt] = __builtin_amdgcn_mfma_f32_16x16x32_bf16(
                    af[rt], bf[nt], acc[rt][nt], 0, 0, 0);
    }
    #pragma unroll
    for (int nt = 0; nt < 4; ++nt) {
        float s = 0.f;
        #pragma unroll
        for (int rt = 0; rt < 4; ++rt)
            #pragma unroll
            for (int r = 0; r < 4; ++r) s += fabsf(acc[rt][nt][r]);
        atomicAdd(&rad_s[nt * 16 + m], s);
    }
    __syncthreads();
    if (tid < N_OUT) atomicAdd(&rad_out[b * N_OUT + tid], rad_s[tid]);
}

// ---------------------------------------------------------------------------
__global__ void combine_k(const float* __restrict__ head_out,
                          const float* __restrict__ rad_out,
                          float* __restrict__ out)
{
    int i = blockIdx.x * 256 + threadIdx.x;
    if (i < BSZ * N_OUT) {
        float h = head_out[i], r = rad_out[i];
        out[i]               = h - r;
        out[BSZ * N_OUT + i] = h + r;
    }
}

// ---------------------------------------------------------------------------
extern "C" void kernel_launch(void* const* d_in, const int* in_sizes, int n_in,
                              void* d_out, int out_size, void* d_ws, size_t ws_size,
                              hipStream_t stream)
{
    const float* X    = (const float*)d_in[0];
    const float* eps  = (const float*)d_in[1];
    const float* Wih  = (const float*)d_in[2];
    const float* Whh  = (const float*)d_in[3];
    const float* bih  = (const float*)d_in[4];
    const float* bhh  = (const float*)d_in[5];
    const float* Wo   = (const float*)d_in[6];
    const float* bo   = (const float*)d_in[7];
    float* out = (float*)d_out;

    const size_t per_sample = (size_t)ESTRIDE * H * 2 + (size_t)H * H * 2
                            + (size_t)N_OUT * H * 2;
    const size_t shared_b = (size_t)H * H * 4 + (size_t)N_OUT * H * 4
                          + (size_t)2 * BSZ * H * 4                      // hp[2]
                          + (size_t)T_STEPS * BSZ * H * 4                // radT
                          + (size_t)3 * BSZ * H * 4                      // lam/de/head_h
                          + (size_t)2 * BSZ * N_OUT * 4 + 256;
    int Bc = BSZ;
    while (Bc > 1 && (size_t)Bc * per_sample + shared_b > ws_size) Bc >>= 1;

    char* p = (char*)d_ws;
    u16* errP      = (u16*)p;   p += (size_t)Bc * ESTRIDE * H * 2;
    u16* WTp       = (u16*)p;   p += (size_t)Bc * H * H * 2;
    u16* WoTp      = (u16*)p;   p += (size_t)Bc * N_OUT * H * 2;
    float* WhhT32  = (float*)p; p += (size_t)H * H * 4;
    float* WoT32   = (float*)p; p += (size_t)N_OUT * H * 4;
    float* hp      = (float*)p; p += (size_t)2 * BSZ * H * 4;
    float* radT    = (float*)p; p += (size_t)T_STEPS * BSZ * H * 4;
    float* lam     = (float*)p; p += (size_t)BSZ * H * 4;
    float* de      = (float*)p; p += (size_t)BSZ * H * 4;
    float* head_h  = (float*)p; p += (size_t)BSZ * H * 4;
    float* head_out= (float*)p; p += (size_t)BSZ * N_OUT * 4;
    float* rad_out = (float*)p;

    init_k<<<(T_STEPS * BSZ * H) / 256, 256, 0, stream>>>(radT);
    transpose_k<<<dim3(H / 32, H / 32), 256, 0, stream>>>(Whh, WhhT32, H, H);
    transpose_k<<<dim3(N_OUT / 32, H / 32), 256, 0, stream>>>(Wo, WoT32, H, N_OUT);

    for (int b0 = 0; b0 < BSZ; b0 += Bc) {
        prep0_k<<<Bc, 256, 0, stream>>>(
            X + (size_t)b0 * N_IN, eps + b0, Wih, bih, bhh,
            hp + (size_t)b0 * H, radT + (size_t)b0 * H, errP);
        for (int t = 1; t < T_STEPS; ++t) {
            int E_old = t * (N_IN + H);
            const float* hp_prev = hp + (size_t)((t - 1) & 1) * BSZ * H + (size_t)b0 * H;
            float*       hp_new  = hp + (size_t)(t & 1) * BSZ * H + (size_t)b0 * H;
            const float* rad_prev = radT + (size_t)(t - 1) * BSZ * H + (size_t)b0 * H;
            float*       rad_new  = radT + (size_t)t * BSZ * H + (size_t)b0 * H;
            mid_k<<<dim3(10, Bc), 256, 0, stream>>>(
                X + (size_t)(t * BSZ + b0) * N_IN, eps + b0, Wih, Whh, WhhT32,
                bih, bhh, hp_prev, rad_prev, hp_new, rad_new, errP, WTp, E_old);
            gemm_k<<<dim3((E_old - H) / 64, Bc), 256, 0, stream>>>(
                errP, WTp, rad_new, E_old - H);
        }
        const float* hp_last = hp + (size_t)((T_STEPS - 1) & 1) * BSZ * H + (size_t)b0 * H;
        const float* rad_last = radT + (size_t)(T_STEPS - 1) * BSZ * H + (size_t)b0 * H;
        tanh_final_k<<<Bc, 256, 0, stream>>>(
            hp_last, rad_last, lam + (size_t)b0 * H, de + (size_t)b0 * H,
            head_h + (size_t)b0 * H);
        packWoT_k<<<Bc, 256, 0, stream>>>(WoT32, lam + (size_t)b0 * H, WoTp);
        head_out_k<<<Bc, 64, 0, stream>>>(
            head_h + (size_t)b0 * H, de + (size_t)b0 * H, Wo, bo,
            head_out + (size_t)b0 * N_OUT, rad_out + (size_t)b0 * N_OUT);
        gemm_out_k<<<dim3(ESTRIDE / 256, Bc), 256, 0, stream>>>(
            errP, WoTp, rad_out + (size_t)b0 * N_OUT);
    }

    combine_k<<<(BSZ * N_OUT + 255) / 256, 256, 0, stream>>>(head_out, rad_out, out);
}

// Round 7
// 2667.248 us; speedup vs baseline: 4.1593x; 1.0216x over previous
//
#include <hip/hip_runtime.h>
#include <math.h>

typedef unsigned short u16;
typedef __attribute__((ext_vector_type(8))) short bf16x8;   // MFMA A/B frag
typedef __attribute__((ext_vector_type(4))) float f32x4;    // MFMA C/D frag

#define T_STEPS 32
#define BSZ     32
#define N_IN    64
#define H       256
#define N_OUT   64
#define ESTRIDE 9984              // rows = 320*31 + 64 (final fresh block)
#define CLAMP_MIN (-2.0f)
#define CLAMP_MAX ( 2.0f)
#define GNB 16                    // gemm blocks per sample

// Fragment-packed layout: chunk = (row>>4)*8 + (k>>5), 512 u16 per chunk,
// within-chunk elem = (((k&31)>>3)*16 + (row&15))*8 + (k&7)
// => A-frag load for (tile,kc) is base + chunk*512 + lane*8, 16B/lane coalesced.

__device__ inline u16 f2bf(float x) {                       // RTNE fp32->bf16
    unsigned u = __builtin_bit_cast(unsigned, x);
    unsigned r = u + 0x7FFFu + ((u >> 16) & 1u);
    return (u16)(r >> 16);
}

// ---------------------------------------------------------------------------
__global__ void init_k(float* __restrict__ radT) {          // zero [T][B][H]
    int i = blockIdx.x * 256 + threadIdx.x;
    radT[i] = 0.0f;
}

// ---------------------------------------------------------------------------
__global__ void transpose_k(const float* __restrict__ src, float* __restrict__ dst,
                            int R, int C)
{
    __shared__ float tile[32][33];
    int bi = blockIdx.y, bj = blockIdx.x;
    int r0 = threadIdx.x >> 5, c = threadIdx.x & 31;
    #pragma unroll
    for (int rr = 0; rr < 4; ++rr) {
        int r = r0 * 4 + rr;
        tile[r][c] = src[(bi * 32 + r) * C + bj * 32 + c];
    }
    __syncthreads();
    #pragma unroll
    for (int rr = 0; rr < 4; ++rr) {
        int r = r0 * 4 + rr;
        dst[(bj * 32 + r) * R + bi * 32 + c] = tile[c][r];
    }
}

// ---------------------------------------------------------------------------
// prep0: head_pre_0, fresh rows [0,64) frag-packed, rad[0]. grid Bc x 256.
// ---------------------------------------------------------------------------
__global__ __launch_bounds__(256) void prep0_k(
    const float* __restrict__ X0, const float* __restrict__ eps,
    const float* __restrict__ Wih, const float* __restrict__ bih,
    const float* __restrict__ bhh,
    float* __restrict__ hp0, float* __restrict__ rad0, u16* __restrict__ err)
{
    __shared__ float hx[N_IN], rr[N_IN], rad_s[H];
    const int b = blockIdx.x, tid = threadIdx.x;
    if (tid < N_IN) {
        float x = X0[b * N_IN + tid], e = eps[b];
        float l = fmaxf(x - e, CLAMP_MIN), u = fminf(x + e, CLAMP_MAX);
        hx[tid] = 0.5f * (l + u);
        rr[tid] = 0.5f * (u - l);
    }
    rad_s[tid] = 0.f;
    __syncthreads();

    float acc = bih[tid] + bhh[tid];
    #pragma unroll 8
    for (int i = 0; i < N_IN; ++i) acc += hx[i] * Wih[i * H + tid];
    hp0[b * H + tid] = acc;

    u16* errB = err + (size_t)b * ESTRIDE * H;
    const int e = tid * 2, q = e >> 7, m = (e >> 3) & 15, j = e & 7;
    #pragma unroll
    for (int ti = 0; ti < 4; ++ti) {
        int i = ti * 16 + m;                 // fresh-row index 0..63
        float rho = rr[i];
        #pragma unroll
        for (int kc = 0; kc < 8; ++kc) {
            int k = kc * 32 + q * 8 + j;
            float v0 = rho * Wih[(size_t)i * H + k];
            float v1 = rho * Wih[(size_t)i * H + k + 1];
            unsigned pk = (unsigned)f2bf(v0) | ((unsigned)f2bf(v1) << 16);
            *(unsigned*)&errB[(size_t)(ti * 8 + kc) * 512 + e] = pk;
            atomicAdd(&rad_s[k], fabsf(v0));
            atomicAdd(&rad_s[k + 1], fabsf(v1));
        }
    }
    __syncthreads();
    atomicAdd(&rad0[b * H + tid], rad_s[tid]);
}

// ---------------------------------------------------------------------------
// mid_k (t>=1): fused tanh(prev) + WT pack + diag rows + fresh rows + head GEMV.
// grid (10, Bc), 256 thr. roles: 0..7 = WT/diag slice, 8 = head, 9 = fresh.
// ---------------------------------------------------------------------------
__global__ __launch_bounds__(256) void mid_k(
    const float* __restrict__ Xt, const float* __restrict__ eps,
    const float* __restrict__ Wih, const float* __restrict__ Whh,
    const float* __restrict__ WhhT32,
    const float* __restrict__ bih, const float* __restrict__ bhh,
    const float* __restrict__ hp_prev, const float* __restrict__ rad_prev,
    float* __restrict__ hp_new, float* __restrict__ rad_new,
    u16* __restrict__ err, u16* __restrict__ WTp, int E_old)
{
    __shared__ float lam_s[H], de_s[H], aux_s[H], hxr[N_IN];
    const int role = blockIdx.x, b = blockIdx.y, tid = threadIdx.x;

    float hd = hp_prev[b * H + tid], r = rad_prev[b * H + tid];
    float l = hd - r, u = hd + r;
    float tl = tanhf(l), tu = tanhf(u);
    float la = fminf(1.f - tl * tl, 1.f - tu * tu);
    float mu = 0.5f * (tu + tl - la * (u + l));
    float dd = 0.5f * (tu - tl - la * (u - l));
    lam_s[tid] = la;
    de_s[tid]  = dd;
    aux_s[tid] = (role == 8) ? (la * hd + mu) : 0.f;   // hh for role 8, rad acc else
    if (tid < N_IN && role >= 8) {
        float x = Xt[b * N_IN + tid], e = eps[b];
        float lo = fmaxf(x - e, CLAMP_MIN), up = fminf(x + e, CLAMP_MAX);
        hxr[tid] = (role == 8) ? 0.5f * (lo + up) : 0.5f * (up - lo);
    }
    __syncthreads();

    if (role == 8) {
        float acc = bih[tid] + bhh[tid];
        #pragma unroll 8
        for (int i = 0; i < N_IN; ++i) acc += hxr[i] * Wih[i * H + tid];
        #pragma unroll 8
        for (int jj = 0; jj < H; ++jj) acc += aux_s[jj] * Whh[jj * H + tid];
        hp_new[b * H + tid] = acc;
        return;
    }

    u16* errB = err + (size_t)b * ESTRIDE * H;
    const int e = tid * 2, q = e >> 7, m = (e >> 3) & 15, j = e & 7;

    if (role < 8) {                            // WT slice + diag rows
        const int s = role;
        const int diag_lo = E_old - H;
        u16* WTb = WTp + (size_t)b * H * H;
        #pragma unroll
        for (int ti = 0; ti < 2; ++ti) {
            int nbase = (2 * s + ti) * 16 + m;       // WT n-row
            int rsrc  = s * 32 + ti * 16 + m;        // diag source index
            float dv  = de_s[rsrc];
            #pragma unroll
            for (int kc = 0; kc < 8; ++kc) {
                int k = kc * 32 + q * 8 + j;
                float w0 = WhhT32[(size_t)nbase * H + k];
                float w1 = WhhT32[(size_t)nbase * H + k + 1];
                unsigned pw = (unsigned)f2bf(lam_s[k] * w0)
                            | ((unsigned)f2bf(lam_s[k + 1] * w1) << 16);
                *(unsigned*)&WTb[(size_t)((2 * s + ti) * 8 + kc) * 512 + e] = pw;
                float v0 = dv * Whh[(size_t)rsrc * H + k];
                float v1 = dv * Whh[(size_t)rsrc * H + k + 1];
                unsigned pv = (unsigned)f2bf(v0) | ((unsigned)f2bf(v1) << 16);
                *(unsigned*)&errB[(size_t)(((diag_lo >> 4) + 2 * s + ti) * 8 + kc) * 512 + e] = pv;
                atomicAdd(&aux_s[k], fabsf(v0));
                atomicAdd(&aux_s[k + 1], fabsf(v1));
            }
        }
    } else {                                   // role 9: fresh rows
        #pragma unroll
        for (int ti = 0; ti < 4; ++ti) {
            int i = ti * 16 + m;
            float rho = hxr[i];
            #pragma unroll
            for (int kc = 0; kc < 8; ++kc) {
                int k = kc * 32 + q * 8 + j;
                float v0 = rho * Wih[(size_t)i * H + k];
                float v1 = rho * Wih[(size_t)i * H + k + 1];
                unsigned pv = (unsigned)f2bf(v0) | ((unsigned)f2bf(v1) << 16);
                *(unsigned*)&errB[(size_t)(((E_old >> 4) + ti) * 8 + kc) * 512 + e] = pv;
                atomicAdd(&aux_s[k], fabsf(v0));
                atomicAdd(&aux_s[k + 1], fabsf(v1));
            }
        }
    }
    __syncthreads();
    atomicAdd(&rad_new[b * H + tid], aux_s[tid]);
}

// ---------------------------------------------------------------------------
// Main MFMA GEMM, in place, frag-packed, persistent-ish:
//   err[0..ntiles*64) <- err @ WT^T, grid (GNB, Bc); block grid-strides tiles.
// Wave w owns cols [w*64,w*64+64): its WT slab lives in 128 VGPRs (loaded
// once). A-frags direct global->reg (16B/lane coalesced). One barrier per
// tile (all waves consume A before in-place store). Wave-private LDS
// transform C-layout -> A-frag layout, then full-line stores.
// rad_new[b,h] += sum_rows |C|.
// ---------------------------------------------------------------------------
__global__ __launch_bounds__(256, 2) void gemm_k(
    u16* __restrict__ err, const u16* __restrict__ WTp,
    float* __restrict__ rad_new, int ntiles)
{
    __shared__ u16 tbuf[4][4096];          // wave-private transform, 32 KB
    __shared__ float rad_s[H];
    const int b = blockIdx.y, tid = threadIdx.x;
    const int wave = tid >> 6, lane = tid & 63;
    const int m = lane & 15, q = lane >> 4;
    u16* errB = err + (size_t)b * ESTRIDE * H;
    const u16* WTb = WTp + (size_t)b * H * H;

    rad_s[tid] = 0.f;

    // B slab -> registers (32 frags = 128 VGPRs), loaded once
    bf16x8 bf[4][8];
    #pragma unroll
    for (int nt = 0; nt < 4; ++nt)
        #pragma unroll
        for (int kc = 0; kc < 8; ++kc)
            bf[nt][kc] = *(const bf16x8*)&WTb[(size_t)((wave * 4 + nt) * 8 + kc) * 512 + lane * 8];

    __syncthreads();   // rad_s visible

    for (int tile = blockIdx.x; tile < ntiles; tile += GNB) {
        f32x4 acc[4][4];
        #pragma unroll
        for (int i = 0; i < 4; ++i)
            #pragma unroll
            for (int c = 0; c < 4; ++c) acc[i][c] = (f32x4){0.f, 0.f, 0.f, 0.f};

        #pragma unroll
        for (int kc = 0; kc < 8; ++kc) {
            bf16x8 af[4];
            #pragma unroll
            for (int rt = 0; rt < 4; ++rt)
                af[rt] = *(const bf16x8*)&errB[(size_t)((tile * 4 + rt) * 8 + kc) * 512 + lane * 8];
            #pragma unroll
            for (int nt = 0; nt < 4; ++nt)
                #pragma unroll
                for (int rt = 0; rt < 4; ++rt)
                    acc[rt][nt] = __builtin_amdgcn_mfma_f32_16x16x32_bf16(
                        af[rt], bf[nt][kc], acc[rt][nt], 0, 0, 0);
        }
        __syncthreads();   // every wave consumed this tile's A before stores

        // transform C (col=lane&15, row=q*4+reg) -> A-frag layout (wave-private)
        u16* W_ = tbuf[wave];
        #pragma unroll
        for (int nt = 0; nt < 4; ++nt) {
            int c32 = (nt & 1) * 16 + m;   // k within 32-chunk
            int q_a = c32 >> 3, jj = c32 & 7, kcl = nt >> 1;
            float s = 0.f;
            #pragma unroll
            for (int rt = 0; rt < 4; ++rt)
                #pragma unroll
                for (int r = 0; r < 4; ++r) {
                    float v = acc[rt][nt][r];
                    s += fabsf(v);
                    W_[rt * 1024 + kcl * 512 + (q_a * 16 + q * 4 + r) * 8 + jj] = f2bf(v);
                }
            atomicAdd(&rad_s[wave * 64 + nt * 16 + m], s);
        }
        // full-line stores from wave-private region (wave-internal ordering)
        #pragma unroll
        for (int rt = 0; rt < 4; ++rt)
            #pragma unroll
            for (int kcl = 0; kcl < 2; ++kcl) {
                uint4 v = *(uint4*)&W_[rt * 1024 + kcl * 512 + lane * 8];
                *(uint4*)&errB[(size_t)((tile * 4 + rt) * 8 + wave * 2 + kcl) * 512 + lane * 8] = v;
            }
    }
    __syncthreads();
    atomicAdd(&rad_new[b * H + tid], rad_s[tid]);
}

// ---------------------------------------------------------------------------
__global__ __launch_bounds__(256) void tanh_final_k(
    const float* __restrict__ hp, const float* __restrict__ rad,
    float* __restrict__ lam, float* __restrict__ de, float* __restrict__ head_h)
{
    const int b = blockIdx.x, h = threadIdx.x;
    float hd = hp[b * H + h], r = rad[b * H + h];
    float l = hd - r, u = hd + r;
    float tl = tanhf(l), tu = tanhf(u);
    float la = fminf(1.f - tl * tl, 1.f - tu * tu);
    float mu = 0.5f * (tu + tl - la * (u + l));
    float dd = 0.5f * (tu - tl - la * (u - l));
    lam[b * H + h] = la;
    de[b * H + h]  = dd;
    head_h[b * H + h] = la * hd + mu;
}

// ---------------------------------------------------------------------------
// pack WoT frag-packed, lam folded. grid Bc x 256.
// ---------------------------------------------------------------------------
__global__ __launch_bounds__(256) void packWoT_k(
    const float* __restrict__ WoT32, const float* __restrict__ lam,
    u16* __restrict__ WoTp)
{
    const int b = blockIdx.x, tid = threadIdx.x;
    __shared__ float lam_s[H];
    lam_s[tid] = lam[b * H + tid];
    __syncthreads();
    u16* dst = WoTp + (size_t)b * N_OUT * H;
    const int e = tid * 2, q = e >> 7, m = (e >> 3) & 15, j = e & 7;
    #pragma unroll
    for (int nt = 0; nt < 4; ++nt) {
        int n = nt * 16 + m;
        #pragma unroll
        for (int kc = 0; kc < 8; ++kc) {
            int k = kc * 32 + q * 8 + j;
            unsigned pw = (unsigned)f2bf(lam_s[k] * WoT32[(size_t)n * H + k])
                        | ((unsigned)f2bf(lam_s[k + 1] * WoT32[(size_t)n * H + k + 1]) << 16);
            *(unsigned*)&dst[(size_t)(nt * 8 + kc) * 512 + e] = pw;
        }
    }
}

// ---------------------------------------------------------------------------
__global__ void head_out_k(
    const float* __restrict__ head_h, const float* __restrict__ de,
    const float* __restrict__ Wo, const float* __restrict__ bo,
    float* __restrict__ head_out, float* __restrict__ rad_out)
{
    const int b = blockIdx.x, o = threadIdx.x;
    float acc = bo[o], accR = 0.f;
    #pragma unroll 4
    for (int j = 0; j < H; ++j) {
        float w = Wo[j * N_OUT + o];
        acc  += head_h[b * H + j] * w;
        accR += fabsf(de[b * H + j] * w);
    }
    head_out[b * N_OUT + o] = acc;
    rad_out[b * N_OUT + o]  = accR;
}

// ---------------------------------------------------------------------------
// final radius: rad_out += sum_rows |err @ WoTp^T| over all ESTRIDE rows.
// Block 256 rows x 64 cols, 4 waves (wave 64x64). grid (ESTRIDE/256, Bc).
// ---------------------------------------------------------------------------
__global__ __launch_bounds__(256) void gemm_out_k(
    const u16* __restrict__ err, const u16* __restrict__ WoTp,
    float* __restrict__ rad_out)
{
    __shared__ float rad_s[N_OUT];
    const int b = blockIdx.y, row0 = blockIdx.x * 256, tid = threadIdx.x;
    const int wave = tid >> 6, lane = tid & 63;
    const int m = lane & 15;
    const u16* errB = err + (size_t)b * ESTRIDE * H;
    const u16* Wb   = WoTp + (size_t)b * N_OUT * H;

    if (tid < N_OUT) rad_s[tid] = 0.f;
    __syncthreads();

    f32x4 acc[4][4];
    #pragma unroll
    for (int i = 0; i < 4; ++i)
        #pragma unroll
        for (int c = 0; c < 4; ++c) acc[i][c] = (f32x4){0.f, 0.f, 0.f, 0.f};

    const int tile0 = (row0 >> 4) + wave * 4;
    #pragma unroll
    for (int kc = 0; kc < 8; ++kc) {
        bf16x8 af[4], bf[4];
        #pragma unroll
        for (int rt = 0; rt < 4; ++rt)
            af[rt] = *(const bf16x8*)&errB[(size_t)((tile0 + rt) * 8 + kc) * 512 + lane * 8];
        #pragma unroll
        for (int nt = 0; nt < 4; ++nt)
            bf[nt] = *(const bf16x8*)&Wb[(size_t)(nt * 8 + kc) * 512 + lane * 8];
        #pragma unroll
        for (int nt = 0; nt < 4; ++nt)
            #pragma unroll
            for (int rt = 0; rt < 4; ++rt)
                acc[rt][nt] = __builtin_amdgcn_mfma_f32_16x16x32_bf16(
                    af[rt], bf[nt], acc[rt][nt], 0, 0, 0);
    }
    #pragma unroll
    for (int nt = 0; nt < 4; ++nt) {
        float s = 0.f;
        #pragma unroll
        for (int rt = 0; rt < 4; ++rt)
            #pragma unroll
            for (int r = 0; r < 4; ++r) s += fabsf(acc[rt][nt][r]);
        atomicAdd(&rad_s[nt * 16 + m], s);
    }
    __syncthreads();
    if (tid < N_OUT) atomicAdd(&rad_out[b * N_OUT + tid], rad_s[tid]);
}

// ---------------------------------------------------------------------------
__global__ void combine_k(const float* __restrict__ head_out,
                          const float* __restrict__ rad_out,
                          float* __restrict__ out)
{
    int i = blockIdx.x * 256 + threadIdx.x;
    if (i < BSZ * N_OUT) {
        float h = head_out[i], r = rad_out[i];
        out[i]               = h - r;
        out[BSZ * N_OUT + i] = h + r;
    }
}

// ---------------------------------------------------------------------------
extern "C" void kernel_launch(void* const* d_in, const int* in_sizes, int n_in,
                              void* d_out, int out_size, void* d_ws, size_t ws_size,
                              hipStream_t stream)
{
    const float* X    = (const float*)d_in[0];
    const float* eps  = (const float*)d_in[1];
    const float* Wih  = (const float*)d_in[2];
    const float* Whh  = (const float*)d_in[3];
    const float* bih  = (const float*)d_in[4];
    const float* bhh  = (const float*)d_in[5];
    const float* Wo   = (const float*)d_in[6];
    const float* bo   = (const float*)d_in[7];
    float* out = (float*)d_out;

    const size_t per_sample = (size_t)ESTRIDE * H * 2 + (size_t)H * H * 2
                            + (size_t)N_OUT * H * 2;
    const size_t shared_b = (size_t)H * H * 4 + (size_t)N_OUT * H * 4
                          + (size_t)2 * BSZ * H * 4                      // hp[2]
                          + (size_t)T_STEPS * BSZ * H * 4                // radT
                          + (size_t)3 * BSZ * H * 4                      // lam/de/head_h
                          + (size_t)2 * BSZ * N_OUT * 4 + 256;
    int Bc = BSZ;
    while (Bc > 1 && (size_t)Bc * per_sample + shared_b > ws_size) Bc >>= 1;

    char* p = (char*)d_ws;
    u16* errP      = (u16*)p;   p += (size_t)Bc * ESTRIDE * H * 2;
    u16* WTp       = (u16*)p;   p += (size_t)Bc * H * H * 2;
    u16* WoTp      = (u16*)p;   p += (size_t)Bc * N_OUT * H * 2;
    float* WhhT32  = (float*)p; p += (size_t)H * H * 4;
    float* WoT32   = (float*)p; p += (size_t)N_OUT * H * 4;
    float* hp      = (float*)p; p += (size_t)2 * BSZ * H * 4;
    float* radT    = (float*)p; p += (size_t)T_STEPS * BSZ * H * 4;
    float* lam     = (float*)p; p += (size_t)BSZ * H * 4;
    float* de      = (float*)p; p += (size_t)BSZ * H * 4;
    float* head_h  = (float*)p; p += (size_t)BSZ * H * 4;
    float* head_out= (float*)p; p += (size_t)BSZ * N_OUT * 4;
    float* rad_out = (float*)p;

    init_k<<<(T_STEPS * BSZ * H) / 256, 256, 0, stream>>>(radT);
    transpose_k<<<dim3(H / 32, H / 32), 256, 0, stream>>>(Whh, WhhT32, H, H);
    transpose_k<<<dim3(N_OUT / 32, H / 32), 256, 0, stream>>>(Wo, WoT32, H, N_OUT);

    for (int b0 = 0; b0 < BSZ; b0 += Bc) {
        prep0_k<<<Bc, 256, 0, stream>>>(
            X + (size_t)b0 * N_IN, eps + b0, Wih, bih, bhh,
            hp + (size_t)b0 * H, radT + (size_t)b0 * H, errP);
        for (int t = 1; t < T_STEPS; ++t) {
            int E_old = t * (N_IN + H);
            int ntiles = (E_old - H) / 64;   // 5t-4
            const float* hp_prev = hp + (size_t)((t - 1) & 1) * BSZ * H + (size_t)b0 * H;
            float*       hp_new  = hp + (size_t)(t & 1) * BSZ * H + (size_t)b0 * H;
            const float* rad_prev = radT + (size_t)(t - 1) * BSZ * H + (size_t)b0 * H;
            float*       rad_new  = radT + (size_t)t * BSZ * H + (size_t)b0 * H;
            mid_k<<<dim3(10, Bc), 256, 0, stream>>>(
                X + (size_t)(t * BSZ + b0) * N_IN, eps + b0, Wih, Whh, WhhT32,
                bih, bhh, hp_prev, rad_prev, hp_new, rad_new, errP, WTp, E_old);
            gemm_k<<<dim3(GNB, Bc), 256, 0, stream>>>(
                errP, WTp, rad_new, ntiles);
        }
        const float* hp_last = hp + (size_t)((T_STEPS - 1) & 1) * BSZ * H + (size_t)b0 * H;
        const float* rad_last = radT + (size_t)(T_STEPS - 1) * BSZ * H + (size_t)b0 * H;
        tanh_final_k<<<Bc, 256, 0, stream>>>(
            hp_last, rad_last, lam + (size_t)b0 * H, de + (size_t)b0 * H,
            head_h + (size_t)b0 * H);
        packWoT_k<<<Bc, 256, 0, stream>>>(WoT32, lam + (size_t)b0 * H, WoTp);
        head_out_k<<<Bc, 64, 0, stream>>>(
            head_h + (size_t)b0 * H, de + (size_t)b0 * H, Wo, bo,
            head_out + (size_t)b0 * N_OUT, rad_out + (size_t)b0 * N_OUT);
        gemm_out_k<<<dim3(ESTRIDE / 256, Bc), 256, 0, stream>>>(
            errP, WoTp, rad_out + (size_t)b0 * N_OUT);
    }

    combine_k<<<(BSZ * N_OUT + 255) / 256, 256, 0, stream>>>(head_out, rad_out, out);
}